// Round 20
// baseline (132.560 us; speedup 1.0000x reference)
//
#include <hip/hip_runtime.h>

#define B_  512
#define S_  200
#define M_  102400

typedef short bf16x8 __attribute__((ext_vector_type(8)));
typedef float f32x4  __attribute__((ext_vector_type(4)));
typedef unsigned short u16;
typedef u16 us4 __attribute__((ext_vector_type(4)));
typedef unsigned int u32;

#define MFMA16 __builtin_amdgcn_mfma_f32_16x16x32_bf16
#define GLDS(gp, lp) __builtin_amdgcn_global_load_lds( \
    (const __attribute__((address_space(1))) unsigned int*)(gp), \
    (__attribute__((address_space(3))) unsigned int*)(lp), 16, 0, 0)

__device__ __forceinline__ u16 f2bf(float f) {
    union { float f; unsigned u; } v; v.f = f;
    unsigned r = v.u + 0x7fffu + ((v.u >> 16) & 1u);
    return (u16)(r >> 16);
}
__device__ __forceinline__ float bf2f(u16 x) {
    union { unsigned u; float f; } v; v.u = ((unsigned)x) << 16;
    return v.f;
}
__device__ __forceinline__ u32 pk(float a, float b) {   // RTZ pack 2xbf16
    return (__float_as_uint(a) >> 16) | (__float_as_uint(b) & 0xffff0000u);
}
__device__ __forceinline__ int swz(int row, int b) { return b ^ ((row & 7) << 4); }

// ws layout (u16 units)
#define WQ_OFF   0
#define WK_OFF   16384
#define WV_OFF   32768
#define W1_OFF   49152    // 8 subs x 16KB: [fr(64)][k(128)] swizzled
#define W2_OFF   114688   // 8 subs x 16KB: [out(128)][lc(64)] swizzled, lc k-permuted
#define BQS_OFF  180224
#define QB_OFF   262144   // also Xb (aliased)
#define KB_OFF   (QB_OFF + 13107200)
#define VB_OFF   (KB_OFF + 13107200)

// ---------------------------------------------------------------------------
__global__ __launch_bounds__(256) void cvt_kernel(
    const float* __restrict__ Wq, const float* __restrict__ bq,
    const float* __restrict__ Wk, const float* __restrict__ Wv,
    const float* __restrict__ W1, const float* __restrict__ W2,
    u16* __restrict__ wdst, float* __restrict__ bqs)
{
    // 1/sqrt(32) * log2(e): scores come out in exp2 domain
    const float QSC = 0.17677669529663689f * 1.4426950408889634f;
    int idx = blockIdx.x * 256 + threadIdx.x;
    if (idx < 128) bqs[idx] = bq[idx] * QSC;
    if (idx < 49152) {
        int wsel = idx >> 14, r = (idx >> 7) & 127, c = idx & 127;
        const float* src = wsel == 0 ? Wq : (wsel == 1 ? Wk : Wv);
        float v = src[idx & 16383];
        if (wsel == 0) v *= QSC;
        *(u16*)((char*)(wdst + wsel * 16384) + r * 256 + swz(r, 2 * c)) = f2bf(v);
    } else if (idx < 114688) {
        int i = idx - 49152;
        int r_g = i >> 7, c = i & 127;
        int sub = r_g >> 6, fr = r_g & 63;
        *(u16*)((char*)(wdst + W1_OFF) + sub * 16384 + fr * 256 + ((2 * c) ^ ((fr & 7) << 4)))
            = f2bf(W1[i]);
    } else if (idx < 180224) {
        int i = idx - 114688;
        int r_out = i >> 9, c_ff = i & 511;
        int sub = c_ff >> 6, o = c_ff & 63;
        int chunk = o >> 5, w32 = o & 31;
        int bb = w32 >> 4, hh = (w32 >> 2) & 3, rr = w32 & 3;
        int lc = chunk * 32 + 8 * hh + 4 * bb + rr;
        *(u16*)((char*)(wdst + W2_OFF) + sub * 16384 + r_out * 128 + ((2 * lc) ^ ((r_out & 7) << 4)))
            = f2bf(W2[i]);
    }
}

// ---------------------------------------------------------------------------
// 3-path projection: blocks [0,800) Q, [800,1600) K, [1600,2400) V.
// Each path stages exactly ONE 32KB weight tile -> 5 blocks/CU residency.
// V path re-reads keys; 52 MB fits L3 (streamed by the K pass) -> L3-hit.
// ---------------------------------------------------------------------------
__global__ __launch_bounds__(256) void proj3_kernel(
    const float* __restrict__ queries, const float* __restrict__ keys,
    const u16* __restrict__ Wqs, const u16* __restrict__ Wks, const u16* __restrict__ Wvs,
    const float* __restrict__ bqs, const float* __restrict__ bk, const float* __restrict__ bv,
    u16* __restrict__ Qb, u16* __restrict__ Kb, u16* __restrict__ Vb)
{
    __shared__ __align__(16) u16 sW[16384];
    const int tid = threadIdx.x, w = tid >> 6, lane = tid & 63;
    const int lo = lane & 15, hi = lane >> 4;
    const int bid = blockIdx.x;
    const int path = bid / 800;          // 0=Q, 1=K, 2=V
    const int base = (bid - path * 800) * 128;

    const u16*   Wsrc = (path == 0) ? Wqs : (path == 1) ? Wks : Wvs;
    const float* X    = (path == 0) ? queries : keys;
    const float* bias = (path == 0) ? bqs : (path == 1) ? bk : bv;

#pragma unroll
    for (int k = 0; k < 8; ++k) {
        int seg = w * 8 + k;
        GLDS((const char*)Wsrc + seg * 1024 + lane * 16, (char*)sW + seg * 1024);
    }

    bf16x8 a[2][4];
#pragma unroll
    for (int t = 0; t < 2; ++t) {
        const float* rp = X + (size_t)(base + w * 32 + t * 16 + lo) * 128;
#pragma unroll
        for (int ks = 0; ks < 4; ++ks) {
            float4 v0 = *(const float4*)(rp + ks * 32 + hi * 8);
            float4 v1 = *(const float4*)(rp + ks * 32 + hi * 8 + 4);
            union { bf16x8 v; u16 s[8]; } af;
            af.s[0]=f2bf(v0.x); af.s[1]=f2bf(v0.y); af.s[2]=f2bf(v0.z); af.s[3]=f2bf(v0.w);
            af.s[4]=f2bf(v1.x); af.s[5]=f2bf(v1.y); af.s[6]=f2bf(v1.z); af.s[7]=f2bf(v1.w);
            a[t][ks] = af.v;
        }
    }
    asm volatile("s_waitcnt vmcnt(0)" ::: "memory");
    __builtin_amdgcn_s_barrier();

#pragma unroll
    for (int n = 0; n < 8; ++n) {
        bf16x8 bf[4];
#pragma unroll
        for (int ks = 0; ks < 4; ++ks)
            bf[ks] = *(const bf16x8*)((const char*)sW + (n*16+lo)*256 + swz(lo, ks*64 + hi*16));
        float bb = bias[n * 16 + lo];
#pragma unroll
        for (int t = 0; t < 2; ++t) {
            f32x4 acc = {0.f, 0.f, 0.f, 0.f};
#pragma unroll
            for (int ks = 0; ks < 4; ++ks) acc = MFMA16(a[t][ks], bf[ks], acc, 0, 0, 0);
            if (path == 0) {
#pragma unroll
                for (int r = 0; r < 4; ++r) {
                    int row = base + w * 32 + t * 16 + hi * 4 + r;
                    *(u16*)((char*)Qb + (size_t)row * 256 + swz(row, n * 32 + 2 * lo)) =
                        f2bf(acc[r] + bb);
                }
            } else {
                u16* dst = (path == 1) ? Kb : Vb;
#pragma unroll
                for (int r = 0; r < 4; ++r) {
                    size_t row = base + w * 32 + t * 16 + hi * 4 + r;
                    dst[row * 128 + n * 16 + lo] = f2bf(acc[r] + bb);
                }
            }
        }
    }
}

// ---------------------------------------------------------------------------
// Attention: r7 structure + mask compaction (unchanged from round 11).
// ---------------------------------------------------------------------------
__global__ __launch_bounds__(256, 4) void attn_kernel(
    const u16* __restrict__ Qb, const u16* __restrict__ Kb, const u16* __restrict__ Vb,
    const int* __restrict__ mask, const float* __restrict__ queries, u16* __restrict__ Xb)
{
    __shared__ __align__(16) u16 sK[224][40];    // slot x d (pad slots zeroed)
    __shared__ __align__(16) u16 sVt[32][248];   // d x permuted slot
    __shared__ __align__(16) u16 sMk[224];       // permuted slot validity (bf16 1/0)
    __shared__ u16 sIdx[224];                    // slot -> original key
    __shared__ int sCnt4[4];

    const int bid = blockIdx.x;
    const int wg  = (bid & 7) * 256 + (bid >> 3);   // XCD-contiguous
    const int b   = wg >> 2;
    const int h   = wg & 3;
    const int tid = threadIdx.x;
    const int w = tid >> 6, lane = tid & 63;
    const int lo = lane & 15, hi = lane >> 4;
    const size_t rowbase = (size_t)b * 200;

    // phase 1: per-wave valid counts + in-wave prefix
    bool valid = (tid < 200) && (mask[rowbase + tid] != 0);
    unsigned long long bal = __ballot(valid);
    int prefix = __popcll(bal & ((1ull << lane) - 1ull));
    if (lane == 0) sCnt4[w] = __popcll(bal);
    __syncthreads();

    // phase 2a: scatter compacted indices + permuted validity mask
    int c0_ = sCnt4[0], c1_ = sCnt4[1], c2_ = sCnt4[2], c3_ = sCnt4[3];
    int off = (w > 0 ? c0_ : 0) + (w > 1 ? c1_ : 0) + (w > 2 ? c2_ : 0);
    const int cnt = c0_ + c1_ + c2_ + c3_;
    const int cntPad = (cnt + 31) & ~31;
    const int nch = cntPad >> 5;
    if (valid) sIdx[off + prefix] = (u16)tid;
    for (int i = tid; i < 224; i += 256) {
        int cb = i & ~31, local = i & 31;
        int hh = local >> 3, j = local & 7;
        int slot = cb + 16 * (j >> 2) + 4 * hh + (j & 3);
        sMk[i] = (slot < cnt) ? (u16)0x3F80 : (u16)0;
    }
    __syncthreads();

    // phase 2b: gather-stage compacted K and permuted V^T
    for (int i = tid; i < (cntPad << 2); i += 256) {
        int j = i >> 2, part = i & 3;
        bf16x8 val = {0,0,0,0,0,0,0,0};
        if (j < cnt) {
            int key = sIdx[j];
            val = *(const bf16x8*)(Kb + (rowbase + key) * 128 + h * 32 + part * 8);
        }
        *(bf16x8*)&sK[j][part * 8] = val;
    }
    for (int slot = tid; slot < (cntPad << 3); slot += 256) {
        int d = slot & 31, sg = slot >> 5;
        int s0 = sg * 4;
        int cb = s0 & ~31, a = (s0 & 31) >> 2;
        int pos = cb + (a & 3) * 8 + (a >> 2) * 4;
        us4 v;
#pragma unroll
        for (int j = 0; j < 4; ++j) {
            int s = s0 + j;
            v[j] = (s < cnt) ? Vb[(rowbase + sIdx[s]) * 128 + h * 32 + d] : (u16)0;
        }
        *(us4*)&sVt[d][pos] = v;
    }
    __syncthreads();

    for (int qb = w; qb < 13; qb += 4) {
        int qrow = qb * 16 + lo;
        if (qrow > 199) qrow = 199;
        bf16x8 qf = *(const bf16x8*)((const char*)Qb + (size_t)(rowbase + qrow) * 256
                                      + swz(qrow, h * 64 + hi * 16));

        f32x4 acc0 = {0.f, 0.f, 0.f, 0.f};
        f32x4 acc1 = {0.f, 0.f, 0.f, 0.f};
        f32x4 accs = {0.f, 0.f, 0.f, 0.f};

#pragma unroll 1
        for (int kt = 0; kt < nch; ++kt) {
            int cb = kt * 32;
            bf16x8 k0 = *(const bf16x8*)&sK[cb + lo][hi * 8];
            bf16x8 k1 = *(const bf16x8*)&sK[cb + 16 + lo][hi * 8];
            f32x4 z = {0.f, 0.f, 0.f, 0.f};
            f32x4 s0 = MFMA16(k0, qf, z, 0, 0, 0);   // S^T[slot=cb+4hi+r][q=lo]
            f32x4 s1 = MFMA16(k1, qf, z, 0, 0, 0);
            float p0 = __builtin_amdgcn_exp2f(s0[0]);
            float p1 = __builtin_amdgcn_exp2f(s0[1]);
            float p2 = __builtin_amdgcn_exp2f(s0[2]);
            float p3 = __builtin_amdgcn_exp2f(s0[3]);
            float p4 = __builtin_amdgcn_exp2f(s1[0]);
            float p5 = __builtin_amdgcn_exp2f(s1[1]);
            float p6 = __builtin_amdgcn_exp2f(s1[2]);
            float p7 = __builtin_amdgcn_exp2f(s1[3]);
            union { bf16x8 v; u32 d[4]; } pa;
            pa.d[0] = pk(p0, p1); pa.d[1] = pk(p2, p3);
            pa.d[2] = pk(p4, p5); pa.d[3] = pk(p6, p7);
            bf16x8 mkf = *(const bf16x8*)&sMk[cb + hi * 8];
            bf16x8 v0  = *(const bf16x8*)&sVt[lo][cb + hi * 8];
            bf16x8 v1  = *(const bf16x8*)&sVt[16 + lo][cb + hi * 8];
            acc0 = MFMA16(pa.v, v0, acc0, 0, 0, 0);
            acc1 = MFMA16(pa.v, v1, acc1, 0, 0, 0);
            accs = MFMA16(pa.v, mkf, accs, 0, 0, 0);   // psum[q=4hi+r] in accs[r]
        }

        float invr[4];
#pragma unroll
        for (int r = 0; r < 4; ++r) invr[r] = __builtin_amdgcn_rcpf(accs[r]);
#pragma unroll
        for (int r = 0; r < 4; ++r) {
            int row = qb * 16 + hi * 4 + r;
            if (row < 200) {
                size_t o  = (rowbase + row) * 128 + h * 32;
                size_t rb = (rowbase + row) * 256;
                *(u16*)((char*)Xb + rb + swz(row, h * 64 + 2 * lo)) =
                    f2bf(acc0[r] * invr[r] + queries[o + lo]);
                *(u16*)((char*)Xb + rb + swz(row, h * 64 + 32 + 2 * lo)) =
                    f2bf(acc1[r] * invr[r] + queries[o + 16 + lo]);
            }
        }
    }
}

// ---------------------------------------------------------------------------
// Fused FFN (r16 v4, best measured): ONE barrier per sub, full double-buffer.
// ---------------------------------------------------------------------------
__global__ __launch_bounds__(256, 2) void ffn_kernel(
    const u16* __restrict__ Xb, const u16* __restrict__ W1s, const u16* __restrict__ W2s,
    const float* __restrict__ b1, const float* __restrict__ b2, float* __restrict__ out)
{
    __shared__ __align__(16) u16 sW1[2][8192];
    __shared__ __align__(16) u16 sW2[2][8192];
    const int tid = threadIdx.x, w = tid >> 6, lane = tid & 63;
    const int lo = lane & 15, hi = lane >> 4;
    const size_t base = (size_t)blockIdx.x * 128;
    const int wrow = w * 32;

    // prologue: stage W1[0] only
#pragma unroll
    for (int k = 0; k < 4; ++k) {
        int seg = w * 4 + k;
        GLDS((const char*)W1s + seg * 1024 + lane * 16, (char*)sW1[0] + seg * 1024);
    }

    bf16x8 a[2][4];
#pragma unroll
    for (int t = 0; t < 2; ++t) {
        size_t row = base + wrow + t * 16 + lo;
#pragma unroll
        for (int ks = 0; ks < 4; ++ks)
            a[t][ks] = *(const bf16x8*)((const char*)Xb + row * 256
                                         + ((ks * 64 + hi * 16) ^ ((lo & 7) << 4)));
    }

    f32x4 yacc[2][8];
#pragma unroll
    for (int t = 0; t < 2; ++t)
#pragma unroll
        for (int n = 0; n < 8; ++n) yacc[t][n] = (f32x4){0.f, 0.f, 0.f, 0.f};

    asm volatile("s_waitcnt vmcnt(0)" ::: "memory");
    __builtin_amdgcn_s_barrier();

    bf16x8 pbPrev[2][2];

#pragma unroll 2
    for (int s = 0; s < 8; ++s) {
        const int cur = s & 1, nxt = cur ^ 1;
        // issue prefetches first (full phase to land)
        if (s < 7) {
#pragma unroll
            for (int k = 0; k < 4; ++k) {
                int seg = w * 4 + k;
                GLDS((const char*)W1s + (s + 1) * 16384 + seg * 1024 + lane * 16,
                     (char*)sW1[nxt] + seg * 1024);
            }
        }
#pragma unroll
        for (int k = 0; k < 4; ++k) {
            int seg = w * 4 + k;
            GLDS((const char*)W2s + s * 16384 + seg * 1024 + lane * 16,
                 (char*)sW2[cur] + seg * 1024);
        }
        // GEMM2(s-1): reads sW2[nxt] = sW2[(s-1)&1]
        if (s > 0) {
#pragma unroll
            for (int c = 0; c < 2; ++c) {
#pragma unroll
                for (int n = 0; n < 8; ++n) {
                    bf16x8 w2f = *(const bf16x8*)((const char*)sW2[nxt]
                                   + (n * 16 + lo) * 128
                                   + ((c * 64 + hi * 16) ^ ((lo & 7) << 4)));
                    yacc[0][n] = MFMA16(w2f, pbPrev[c][0], yacc[0][n], 0, 0, 0);
                    yacc[1][n] = MFMA16(w2f, pbPrev[c][1], yacc[1][n], 0, 0, 0);
                }
            }
        }
        // GEMM1(s): reads sW1[cur] -> pbPrev for next phase
#pragma unroll
        for (int c = 0; c < 2; ++c) {
            bf16x8 w1f[2][4];
#pragma unroll
            for (int u = 0; u < 2; ++u)
#pragma unroll
                for (int ks = 0; ks < 4; ++ks)
                    w1f[u][ks] = *(const bf16x8*)((const char*)sW1[cur]
                                   + ((2*c+u) * 16 + lo) * 256
                                   + ((ks * 64 + hi * 16) ^ ((lo & 7) << 4)));
            float4 b1v0 = *(const float4*)(b1 + s * 64 + (2*c) * 16 + 4 * hi);
            float4 b1v1 = *(const float4*)(b1 + s * 64 + (2*c+1) * 16 + 4 * hi);
#pragma unroll
            for (int t = 0; t < 2; ++t) {
                f32x4 h0 = {0.f,0.f,0.f,0.f}, h1 = {0.f,0.f,0.f,0.f};
#pragma unroll
                for (int ks = 0; ks < 4; ++ks) {
                    h0 = MFMA16(w1f[0][ks], a[t][ks], h0, 0, 0, 0);
                    h1 = MFMA16(w1f[1][ks], a[t][ks], h1, 0, 0, 0);
                }
                float p0 = fmaxf(h0[0] + b1v0.x, 0.f);
                float p1 = fmaxf(h0[1] + b1v0.y, 0.f);
                float p2 = fmaxf(h0[2] + b1v0.z, 0.f);
                float p3 = fmaxf(h0[3] + b1v0.w, 0.f);
                float p4 = fmaxf(h1[0] + b1v1.x, 0.f);
                float p5 = fmaxf(h1[1] + b1v1.y, 0.f);
                float p6 = fmaxf(h1[2] + b1v1.z, 0.f);
                float p7 = fmaxf(h1[3] + b1v1.w, 0.f);
                union { bf16x8 v; u32 d[4]; } pu;
                pu.d[0] = pk(p0, p1); pu.d[1] = pk(p2, p3);
                pu.d[2] = pk(p4, p5); pu.d[3] = pk(p6, p7);
                pbPrev[c][t] = pu.v;
            }
        }
        asm volatile("s_waitcnt vmcnt(0)" ::: "memory");
        __builtin_amdgcn_s_barrier();
    }

    // epilogue GEMM2(7): reads sW2[1] (staged+drained in phase 7)
#pragma unroll
    for (int c = 0; c < 2; ++c) {
#pragma unroll
        for (int n = 0; n < 8; ++n) {
            bf16x8 w2f = *(const bf16x8*)((const char*)sW2[1]
                           + (n * 16 + lo) * 128
                           + ((c * 64 + hi * 16) ^ ((lo & 7) << 4)));
            yacc[0][n] = MFMA16(w2f, pbPrev[c][0], yacc[0][n], 0, 0, 0);
            yacc[1][n] = MFMA16(w2f, pbPrev[c][1], yacc[1][n], 0, 0, 0);
        }
    }

    // store epilogue: lane holds Y[Xrow=wrow+t*16+lo][out=n*16+4hi+r]
#pragma unroll
    for (int t = 0; t < 2; ++t) {
        size_t row = base + wrow + t * 16 + lo;
#pragma unroll
        for (int n = 0; n < 8; ++n) {
            float4 b2v = *(const float4*)(b2 + n * 16 + 4 * hi);
            us4 rv = *(const us4*)((const char*)Xb + row * 256
                                    + ((2 * (n * 16 + 4 * hi)) ^ (((int)row & 7) << 4)));
            float4 o;
            o.x = yacc[t][n][0] + b2v.x + bf2f(rv[0]);
            o.y = yacc[t][n][1] + b2v.y + bf2f(rv[1]);
            o.z = yacc[t][n][2] + b2v.z + bf2f(rv[2]);
            o.w = yacc[t][n][3] + b2v.w + bf2f(rv[3]);
            *(float4*)(out + row * 128 + n * 16 + 4 * hi) = o;
        }
    }
}

// ---------------------------------------------------------------------------
extern "C" void kernel_launch(void* const* d_in, const int* in_sizes, int n_in,
                              void* d_out, int out_size, void* d_ws, size_t ws_size,
                              hipStream_t stream) {
    const float* queries = (const float*)d_in[0];
    const float* keys    = (const float*)d_in[1];
    const int*   mask    = (const int*)d_in[2];
    const float* Wq = (const float*)d_in[3];
    const float* bq = (const float*)d_in[4];
    const float* Wk = (const float*)d_in[5];
    const float* bk = (const float*)d_in[6];
    const float* Wv = (const float*)d_in[7];
    const float* bv = (const float*)d_in[8];
    const float* W1 = (const float*)d_in[9];
    const float* b1 = (const float*)d_in[10];
    const float* W2 = (const float*)d_in[11];
    const float* b2 = (const float*)d_in[12];
    float* out = (float*)d_out;

    u16* wbase = (u16*)d_ws;
    u16* Qb = wbase + QB_OFF;   // also Xb
    u16* Kb = wbase + KB_OFF;
    u16* Vb = wbase + VB_OFF;
    float* bqs = (float*)(wbase + BQS_OFF);

    cvt_kernel<<<704, 256, 0, stream>>>(Wq, bq, Wk, Wv, W1, W2, wbase, bqs);
    proj3_kernel<<<2400, 256, 0, stream>>>(queries, keys,
                                           wbase + WQ_OFF, wbase + WK_OFF, wbase + WV_OFF,
                                           bqs, bk, bv, Qb, Kb, Vb);
    attn_kernel<<<B_ * 4, 256, 0, stream>>>(Qb, Kb, Vb, mask, queries, Qb);
    ffn_kernel<<<800, 256, 0, stream>>>(Qb, wbase + W1_OFF, wbase + W2_OFF, b1, b2, out);
}

// Round 21
// 127.056 us; speedup vs baseline: 1.0433x; 1.0433x over previous
//
#include <hip/hip_runtime.h>

#define B_  512
#define S_  200
#define M_  102400

typedef short bf16x8 __attribute__((ext_vector_type(8)));
typedef float f32x4  __attribute__((ext_vector_type(4)));
typedef unsigned short u16;
typedef u16 us4 __attribute__((ext_vector_type(4)));
typedef unsigned int u32;

#define MFMA16 __builtin_amdgcn_mfma_f32_16x16x32_bf16
#define GLDS(gp, lp) __builtin_amdgcn_global_load_lds( \
    (const __attribute__((address_space(1))) unsigned int*)(gp), \
    (__attribute__((address_space(3))) unsigned int*)(lp), 16, 0, 0)

__device__ __forceinline__ u16 f2bf(float f) {
    union { float f; unsigned u; } v; v.f = f;
    unsigned r = v.u + 0x7fffu + ((v.u >> 16) & 1u);
    return (u16)(r >> 16);
}
__device__ __forceinline__ float bf2f(u16 x) {
    union { unsigned u; float f; } v; v.u = ((unsigned)x) << 16;
    return v.f;
}
__device__ __forceinline__ u32 pk(float a, float b) {   // RTZ pack 2xbf16
    return (__float_as_uint(a) >> 16) | (__float_as_uint(b) & 0xffff0000u);
}
__device__ __forceinline__ int swz(int row, int b) { return b ^ ((row & 7) << 4); }

// ws layout (u16 units)
#define WQ_OFF   0
#define WK_OFF   16384
#define WV_OFF   32768
#define W1_OFF   49152    // 8 subs x 16KB: [fr(64)][k(128)] swizzled
#define W2_OFF   114688   // 8 subs x 16KB: [out(128)][lc(64)] swizzled, lc k-permuted
#define BQS_OFF  180224
#define QB_OFF   262144   // also Xb (aliased)
#define KB_OFF   (QB_OFF + 13107200)
#define VB_OFF   (KB_OFF + 13107200)

// ---------------------------------------------------------------------------
__global__ __launch_bounds__(256) void cvt_kernel(
    const float* __restrict__ Wq, const float* __restrict__ bq,
    const float* __restrict__ Wk, const float* __restrict__ Wv,
    const float* __restrict__ W1, const float* __restrict__ W2,
    u16* __restrict__ wdst, float* __restrict__ bqs)
{
    // 1/sqrt(32) * log2(e): scores come out in exp2 domain
    const float QSC = 0.17677669529663689f * 1.4426950408889634f;
    int idx = blockIdx.x * 256 + threadIdx.x;
    if (idx < 128) bqs[idx] = bq[idx] * QSC;
    if (idx < 49152) {
        int wsel = idx >> 14, r = (idx >> 7) & 127, c = idx & 127;
        const float* src = wsel == 0 ? Wq : (wsel == 1 ? Wk : Wv);
        float v = src[idx & 16383];
        if (wsel == 0) v *= QSC;
        *(u16*)((char*)(wdst + wsel * 16384) + r * 256 + swz(r, 2 * c)) = f2bf(v);
    } else if (idx < 114688) {
        int i = idx - 49152;
        int r_g = i >> 7, c = i & 127;
        int sub = r_g >> 6, fr = r_g & 63;
        *(u16*)((char*)(wdst + W1_OFF) + sub * 16384 + fr * 256 + ((2 * c) ^ ((fr & 7) << 4)))
            = f2bf(W1[i]);
    } else if (idx < 180224) {
        int i = idx - 114688;
        int r_out = i >> 9, c_ff = i & 511;
        int sub = c_ff >> 6, o = c_ff & 63;
        int chunk = o >> 5, w32 = o & 31;
        int bb = w32 >> 4, hh = (w32 >> 2) & 3, rr = w32 & 3;
        int lc = chunk * 32 + 8 * hh + 4 * bb + rr;
        *(u16*)((char*)(wdst + W2_OFF) + sub * 16384 + r_out * 128 + ((2 * lc) ^ ((r_out & 7) << 4)))
            = f2bf(W2[i]);
    }
}

// ---------------------------------------------------------------------------
// FUSED projections, 32 KB LDS (5 blocks/CU): blocks [0,800) = Q path;
// [800,1600) = KV path with SEQUENTIAL Wk -> Wv staging into the same sW
// (keys read once into regs, reused for both GEMMs).
// ---------------------------------------------------------------------------
__global__ __launch_bounds__(256) void proj_qkv_kernel(
    const float* __restrict__ queries, const float* __restrict__ keys,
    const u16* __restrict__ Wqs, const u16* __restrict__ Wks, const u16* __restrict__ Wvs,
    const float* __restrict__ bqs, const float* __restrict__ bk, const float* __restrict__ bv,
    u16* __restrict__ Qb, u16* __restrict__ Kb, u16* __restrict__ Vb)
{
    __shared__ __align__(16) u16 sW[16384];
    const int tid = threadIdx.x, w = tid >> 6, lane = tid & 63;
    const int lo = lane & 15, hi = lane >> 4;
    const int bid = blockIdx.x;

    if (bid < 800) {
        // ---------------- Q path ----------------
        const int base = bid * 128;
#pragma unroll
        for (int k = 0; k < 8; ++k) {
            int seg = w * 8 + k;
            GLDS((const char*)Wqs + seg * 1024 + lane * 16, (char*)sW + seg * 1024);
        }
        bf16x8 a[2][4];
#pragma unroll
        for (int t = 0; t < 2; ++t) {
            const float* rp = queries + (size_t)(base + w * 32 + t * 16 + lo) * 128;
#pragma unroll
            for (int ks = 0; ks < 4; ++ks) {
                float4 v0 = *(const float4*)(rp + ks * 32 + hi * 8);
                float4 v1 = *(const float4*)(rp + ks * 32 + hi * 8 + 4);
                union { bf16x8 v; u16 s[8]; } af;
                af.s[0]=f2bf(v0.x); af.s[1]=f2bf(v0.y); af.s[2]=f2bf(v0.z); af.s[3]=f2bf(v0.w);
                af.s[4]=f2bf(v1.x); af.s[5]=f2bf(v1.y); af.s[6]=f2bf(v1.z); af.s[7]=f2bf(v1.w);
                a[t][ks] = af.v;
            }
        }
        asm volatile("s_waitcnt vmcnt(0)" ::: "memory");
        __builtin_amdgcn_s_barrier();

#pragma unroll
        for (int n = 0; n < 8; ++n) {
            bf16x8 bf[4];
#pragma unroll
            for (int ks = 0; ks < 4; ++ks)
                bf[ks] = *(const bf16x8*)((const char*)sW + (n*16+lo)*256 + swz(lo, ks*64 + hi*16));
            float bb = bqs[n * 16 + lo];
#pragma unroll
            for (int t = 0; t < 2; ++t) {
                f32x4 acc = {0.f, 0.f, 0.f, 0.f};
#pragma unroll
                for (int ks = 0; ks < 4; ++ks) acc = MFMA16(a[t][ks], bf[ks], acc, 0, 0, 0);
#pragma unroll
                for (int r = 0; r < 4; ++r) {
                    int row = base + w * 32 + t * 16 + hi * 4 + r;
                    *(u16*)((char*)Qb + (size_t)row * 256 + swz(row, n * 32 + 2 * lo)) =
                        f2bf(acc[r] + bb);
                }
            }
        }
    } else {
        // ---------------- KV path (sequential Wk -> Wv in one 32KB sW) ------
        const int base = (bid - 800) * 128;
#pragma unroll
        for (int k = 0; k < 8; ++k) {
            int seg = w * 8 + k;
            GLDS((const char*)Wks + seg * 1024 + lane * 16, (char*)sW + seg * 1024);
        }
        bf16x8 a[2][4];
#pragma unroll
        for (int t = 0; t < 2; ++t) {
            const float* rp = keys + (size_t)(base + w * 32 + t * 16 + lo) * 128;
#pragma unroll
            for (int ks = 0; ks < 4; ++ks) {
                float4 v0 = *(const float4*)(rp + ks * 32 + hi * 8);
                float4 v1 = *(const float4*)(rp + ks * 32 + hi * 8 + 4);
                union { bf16x8 v; u16 s[8]; } af;
                af.s[0]=f2bf(v0.x); af.s[1]=f2bf(v0.y); af.s[2]=f2bf(v0.z); af.s[3]=f2bf(v0.w);
                af.s[4]=f2bf(v1.x); af.s[5]=f2bf(v1.y); af.s[6]=f2bf(v1.z); af.s[7]=f2bf(v1.w);
                a[t][ks] = af.v;
            }
        }
        asm volatile("s_waitcnt vmcnt(0)" ::: "memory");
        __builtin_amdgcn_s_barrier();

        // K GEMM (each wave's sW ds_reads are consumed by its MFMAs before
        // it reaches the next barrier -> safe to overwrite sW after it)
#pragma unroll
        for (int n = 0; n < 8; ++n) {
            bf16x8 bf[4];
#pragma unroll
            for (int ks = 0; ks < 4; ++ks)
                bf[ks] = *(const bf16x8*)((const char*)sW + (n*16+lo)*256 + swz(lo, ks*64 + hi*16));
            float bb = bk[n * 16 + lo];
#pragma unroll
            for (int t = 0; t < 2; ++t) {
                f32x4 acc = {0.f, 0.f, 0.f, 0.f};
#pragma unroll
                for (int ks = 0; ks < 4; ++ks) acc = MFMA16(a[t][ks], bf[ks], acc, 0, 0, 0);
#pragma unroll
                for (int r = 0; r < 4; ++r) {
                    size_t row = base + w * 32 + t * 16 + hi * 4 + r;
                    Kb[row * 128 + n * 16 + lo] = f2bf(acc[r] + bb);
                }
            }
        }
        __builtin_amdgcn_s_barrier();   // all sW reads done
#pragma unroll
        for (int k = 0; k < 8; ++k) {
            int seg = w * 8 + k;
            GLDS((const char*)Wvs + seg * 1024 + lane * 16, (char*)sW + seg * 1024);
        }
        asm volatile("s_waitcnt vmcnt(0)" ::: "memory");
        __builtin_amdgcn_s_barrier();

        // V GEMM (same keys fragments from regs)
#pragma unroll
        for (int n = 0; n < 8; ++n) {
            bf16x8 bf[4];
#pragma unroll
            for (int ks = 0; ks < 4; ++ks)
                bf[ks] = *(const bf16x8*)((const char*)sW + (n*16+lo)*256 + swz(lo, ks*64 + hi*16));
            float bb = bv[n * 16 + lo];
#pragma unroll
            for (int t = 0; t < 2; ++t) {
                f32x4 acc = {0.f, 0.f, 0.f, 0.f};
#pragma unroll
                for (int ks = 0; ks < 4; ++ks) acc = MFMA16(a[t][ks], bf[ks], acc, 0, 0, 0);
#pragma unroll
                for (int r = 0; r < 4; ++r) {
                    size_t row = base + w * 32 + t * 16 + hi * 4 + r;
                    Vb[row * 128 + n * 16 + lo] = f2bf(acc[r] + bb);
                }
            }
        }
    }
}

// ---------------------------------------------------------------------------
// Attention: r7 structure + mask compaction (unchanged from round 11).
// ---------------------------------------------------------------------------
__global__ __launch_bounds__(256, 4) void attn_kernel(
    const u16* __restrict__ Qb, const u16* __restrict__ Kb, const u16* __restrict__ Vb,
    const int* __restrict__ mask, const float* __restrict__ queries, u16* __restrict__ Xb)
{
    __shared__ __align__(16) u16 sK[224][40];    // slot x d (pad slots zeroed)
    __shared__ __align__(16) u16 sVt[32][248];   // d x permuted slot
    __shared__ __align__(16) u16 sMk[224];       // permuted slot validity (bf16 1/0)
    __shared__ u16 sIdx[224];                    // slot -> original key
    __shared__ int sCnt4[4];

    const int bid = blockIdx.x;
    const int wg  = (bid & 7) * 256 + (bid >> 3);   // XCD-contiguous
    const int b   = wg >> 2;
    const int h   = wg & 3;
    const int tid = threadIdx.x;
    const int w = tid >> 6, lane = tid & 63;
    const int lo = lane & 15, hi = lane >> 4;
    const size_t rowbase = (size_t)b * 200;

    // phase 1: per-wave valid counts + in-wave prefix
    bool valid = (tid < 200) && (mask[rowbase + tid] != 0);
    unsigned long long bal = __ballot(valid);
    int prefix = __popcll(bal & ((1ull << lane) - 1ull));
    if (lane == 0) sCnt4[w] = __popcll(bal);
    __syncthreads();

    // phase 2a: scatter compacted indices + permuted validity mask
    int c0_ = sCnt4[0], c1_ = sCnt4[1], c2_ = sCnt4[2], c3_ = sCnt4[3];
    int off = (w > 0 ? c0_ : 0) + (w > 1 ? c1_ : 0) + (w > 2 ? c2_ : 0);
    const int cnt = c0_ + c1_ + c2_ + c3_;
    const int cntPad = (cnt + 31) & ~31;
    const int nch = cntPad >> 5;
    if (valid) sIdx[off + prefix] = (u16)tid;
    for (int i = tid; i < 224; i += 256) {
        int cb = i & ~31, local = i & 31;
        int hh = local >> 3, j = local & 7;
        int slot = cb + 16 * (j >> 2) + 4 * hh + (j & 3);
        sMk[i] = (slot < cnt) ? (u16)0x3F80 : (u16)0;
    }
    __syncthreads();

    // phase 2b: gather-stage compacted K and permuted V^T
    for (int i = tid; i < (cntPad << 2); i += 256) {
        int j = i >> 2, part = i & 3;
        bf16x8 val = {0,0,0,0,0,0,0,0};
        if (j < cnt) {
            int key = sIdx[j];
            val = *(const bf16x8*)(Kb + (rowbase + key) * 128 + h * 32 + part * 8);
        }
        *(bf16x8*)&sK[j][part * 8] = val;
    }
    for (int slot = tid; slot < (cntPad << 3); slot += 256) {
        int d = slot & 31, sg = slot >> 5;
        int s0 = sg * 4;
        int cb = s0 & ~31, a = (s0 & 31) >> 2;
        int pos = cb + (a & 3) * 8 + (a >> 2) * 4;
        us4 v;
#pragma unroll
        for (int j = 0; j < 4; ++j) {
            int s = s0 + j;
            v[j] = (s < cnt) ? Vb[(rowbase + sIdx[s]) * 128 + h * 32 + d] : (u16)0;
        }
        *(us4*)&sVt[d][pos] = v;
    }
    __syncthreads();

    for (int qb = w; qb < 13; qb += 4) {
        int qrow = qb * 16 + lo;
        if (qrow > 199) qrow = 199;
        bf16x8 qf = *(const bf16x8*)((const char*)Qb + (size_t)(rowbase + qrow) * 256
                                      + swz(qrow, h * 64 + hi * 16));

        f32x4 acc0 = {0.f, 0.f, 0.f, 0.f};
        f32x4 acc1 = {0.f, 0.f, 0.f, 0.f};
        f32x4 accs = {0.f, 0.f, 0.f, 0.f};

#pragma unroll 1
        for (int kt = 0; kt < nch; ++kt) {
            int cb = kt * 32;
            bf16x8 k0 = *(const bf16x8*)&sK[cb + lo][hi * 8];
            bf16x8 k1 = *(const bf16x8*)&sK[cb + 16 + lo][hi * 8];
            f32x4 z = {0.f, 0.f, 0.f, 0.f};
            f32x4 s0 = MFMA16(k0, qf, z, 0, 0, 0);   // S^T[slot=cb+4hi+r][q=lo]
            f32x4 s1 = MFMA16(k1, qf, z, 0, 0, 0);
            float p0 = __builtin_amdgcn_exp2f(s0[0]);
            float p1 = __builtin_amdgcn_exp2f(s0[1]);
            float p2 = __builtin_amdgcn_exp2f(s0[2]);
            float p3 = __builtin_amdgcn_exp2f(s0[3]);
            float p4 = __builtin_amdgcn_exp2f(s1[0]);
            float p5 = __builtin_amdgcn_exp2f(s1[1]);
            float p6 = __builtin_amdgcn_exp2f(s1[2]);
            float p7 = __builtin_amdgcn_exp2f(s1[3]);
            union { bf16x8 v; u32 d[4]; } pa;
            pa.d[0] = pk(p0, p1); pa.d[1] = pk(p2, p3);
            pa.d[2] = pk(p4, p5); pa.d[3] = pk(p6, p7);
            bf16x8 mkf = *(const bf16x8*)&sMk[cb + hi * 8];
            bf16x8 v0  = *(const bf16x8*)&sVt[lo][cb + hi * 8];
            bf16x8 v1  = *(const bf16x8*)&sVt[16 + lo][cb + hi * 8];
            acc0 = MFMA16(pa.v, v0, acc0, 0, 0, 0);
            acc1 = MFMA16(pa.v, v1, acc1, 0, 0, 0);
            accs = MFMA16(pa.v, mkf, accs, 0, 0, 0);   // psum[q=4hi+r] in accs[r]
        }

        float invr[4];
#pragma unroll
        for (int r = 0; r < 4; ++r) invr[r] = __builtin_amdgcn_rcpf(accs[r]);
#pragma unroll
        for (int r = 0; r < 4; ++r) {
            int row = qb * 16 + hi * 4 + r;
            if (row < 200) {
                size_t o  = (rowbase + row) * 128 + h * 32;
                size_t rb = (rowbase + row) * 256;
                *(u16*)((char*)Xb + rb + swz(row, h * 64 + 2 * lo)) =
                    f2bf(acc0[r] * invr[r] + queries[o + lo]);
                *(u16*)((char*)Xb + rb + swz(row, h * 64 + 32 + 2 * lo)) =
                    f2bf(acc1[r] * invr[r] + queries[o + 16 + lo]);
            }
        }
    }
}

// ---------------------------------------------------------------------------
// Fused FFN (r16 v4, best measured): ONE barrier per sub, full double-buffer.
// ---------------------------------------------------------------------------
__global__ __launch_bounds__(256, 2) void ffn_kernel(
    const u16* __restrict__ Xb, const u16* __restrict__ W1s, const u16* __restrict__ W2s,
    const float* __restrict__ b1, const float* __restrict__ b2, float* __restrict__ out)
{
    __shared__ __align__(16) u16 sW1[2][8192];
    __shared__ __align__(16) u16 sW2[2][8192];
    const int tid = threadIdx.x, w = tid >> 6, lane = tid & 63;
    const int lo = lane & 15, hi = lane >> 4;
    const size_t base = (size_t)blockIdx.x * 128;
    const int wrow = w * 32;

    // prologue: stage W1[0] only
#pragma unroll
    for (int k = 0; k < 4; ++k) {
        int seg = w * 4 + k;
        GLDS((const char*)W1s + seg * 1024 + lane * 16, (char*)sW1[0] + seg * 1024);
    }

    bf16x8 a[2][4];
#pragma unroll
    for (int t = 0; t < 2; ++t) {
        size_t row = base + wrow + t * 16 + lo;
#pragma unroll
        for (int ks = 0; ks < 4; ++ks)
            a[t][ks] = *(const bf16x8*)((const char*)Xb + row * 256
                                         + ((ks * 64 + hi * 16) ^ ((lo & 7) << 4)));
    }

    f32x4 yacc[2][8];
#pragma unroll
    for (int t = 0; t < 2; ++t)
#pragma unroll
        for (int n = 0; n < 8; ++n) yacc[t][n] = (f32x4){0.f, 0.f, 0.f, 0.f};

    asm volatile("s_waitcnt vmcnt(0)" ::: "memory");
    __builtin_amdgcn_s_barrier();

    bf16x8 pbPrev[2][2];

#pragma unroll 2
    for (int s = 0; s < 8; ++s) {
        const int cur = s & 1, nxt = cur ^ 1;
        // issue prefetches first (full phase to land)
        if (s < 7) {
#pragma unroll
            for (int k = 0; k < 4; ++k) {
                int seg = w * 4 + k;
                GLDS((const char*)W1s + (s + 1) * 16384 + seg * 1024 + lane * 16,
                     (char*)sW1[nxt] + seg * 1024);
            }
        }
#pragma unroll
        for (int k = 0; k < 4; ++k) {
            int seg = w * 4 + k;
            GLDS((const char*)W2s + s * 16384 + seg * 1024 + lane * 16,
                 (char*)sW2[cur] + seg * 1024);
        }
        // GEMM2(s-1): reads sW2[nxt] = sW2[(s-1)&1]
        if (s > 0) {
#pragma unroll
            for (int c = 0; c < 2; ++c) {
#pragma unroll
                for (int n = 0; n < 8; ++n) {
                    bf16x8 w2f = *(const bf16x8*)((const char*)sW2[nxt]
                                   + (n * 16 + lo) * 128
                                   + ((c * 64 + hi * 16) ^ ((lo & 7) << 4)));
                    yacc[0][n] = MFMA16(w2f, pbPrev[c][0], yacc[0][n], 0, 0, 0);
                    yacc[1][n] = MFMA16(w2f, pbPrev[c][1], yacc[1][n], 0, 0, 0);
                }
            }
        }
        // GEMM1(s): reads sW1[cur] -> pbPrev for next phase
#pragma unroll
        for (int c = 0; c < 2; ++c) {
            bf16x8 w1f[2][4];
#pragma unroll
            for (int u = 0; u < 2; ++u)
#pragma unroll
                for (int ks = 0; ks < 4; ++ks)
                    w1f[u][ks] = *(const bf16x8*)((const char*)sW1[cur]
                                   + ((2*c+u) * 16 + lo) * 256
                                   + ((ks * 64 + hi * 16) ^ ((lo & 7) << 4)));
            float4 b1v0 = *(const float4*)(b1 + s * 64 + (2*c) * 16 + 4 * hi);
            float4 b1v1 = *(const float4*)(b1 + s * 64 + (2*c+1) * 16 + 4 * hi);
#pragma unroll
            for (int t = 0; t < 2; ++t) {
                f32x4 h0 = {0.f,0.f,0.f,0.f}, h1 = {0.f,0.f,0.f,0.f};
#pragma unroll
                for (int ks = 0; ks < 4; ++ks) {
                    h0 = MFMA16(w1f[0][ks], a[t][ks], h0, 0, 0, 0);
                    h1 = MFMA16(w1f[1][ks], a[t][ks], h1, 0, 0, 0);
                }
                float p0 = fmaxf(h0[0] + b1v0.x, 0.f);
                float p1 = fmaxf(h0[1] + b1v0.y, 0.f);
                float p2 = fmaxf(h0[2] + b1v0.z, 0.f);
                float p3 = fmaxf(h0[3] + b1v0.w, 0.f);
                float p4 = fmaxf(h1[0] + b1v1.x, 0.f);
                float p5 = fmaxf(h1[1] + b1v1.y, 0.f);
                float p6 = fmaxf(h1[2] + b1v1.z, 0.f);
                float p7 = fmaxf(h1[3] + b1v1.w, 0.f);
                union { bf16x8 v; u32 d[4]; } pu;
                pu.d[0] = pk(p0, p1); pu.d[1] = pk(p2, p3);
                pu.d[2] = pk(p4, p5); pu.d[3] = pk(p6, p7);
                pbPrev[c][t] = pu.v;
            }
        }
        asm volatile("s_waitcnt vmcnt(0)" ::: "memory");
        __builtin_amdgcn_s_barrier();
    }

    // epilogue GEMM2(7): reads sW2[1] (staged+drained in phase 7)
#pragma unroll
    for (int c = 0; c < 2; ++c) {
#pragma unroll
        for (int n = 0; n < 8; ++n) {
            bf16x8 w2f = *(const bf16x8*)((const char*)sW2[1]
                           + (n * 16 + lo) * 128
                           + ((c * 64 + hi * 16) ^ ((lo & 7) << 4)));
            yacc[0][n] = MFMA16(w2f, pbPrev[c][0], yacc[0][n], 0, 0, 0);
            yacc[1][n] = MFMA16(w2f, pbPrev[c][1], yacc[1][n], 0, 0, 0);
        }
    }

    // store epilogue: lane holds Y[Xrow=wrow+t*16+lo][out=n*16+4hi+r]
#pragma unroll
    for (int t = 0; t < 2; ++t) {
        size_t row = base + wrow + t * 16 + lo;
#pragma unroll
        for (int n = 0; n < 8; ++n) {
            float4 b2v = *(const float4*)(b2 + n * 16 + 4 * hi);
            us4 rv = *(const us4*)((const char*)Xb + row * 256
                                    + ((2 * (n * 16 + 4 * hi)) ^ (((int)row & 7) << 4)));
            float4 o;
            o.x = yacc[t][n][0] + b2v.x + bf2f(rv[0]);
            o.y = yacc[t][n][1] + b2v.y + bf2f(rv[1]);
            o.z = yacc[t][n][2] + b2v.z + bf2f(rv[2]);
            o.w = yacc[t][n][3] + b2v.w + bf2f(rv[3]);
            *(float4*)(out + row * 128 + n * 16 + 4 * hi) = o;
        }
    }
}

// ---------------------------------------------------------------------------
extern "C" void kernel_launch(void* const* d_in, const int* in_sizes, int n_in,
                              void* d_out, int out_size, void* d_ws, size_t ws_size,
                              hipStream_t stream) {
    const float* queries = (const float*)d_in[0];
    const float* keys    = (const float*)d_in[1];
    const int*   mask    = (const int*)d_in[2];
    const float* Wq = (const float*)d_in[3];
    const float* bq = (const float*)d_in[4];
    const float* Wk = (const float*)d_in[5];
    const float* bk = (const float*)d_in[6];
    const float* Wv = (const float*)d_in[7];
    const float* bv = (const float*)d_in[8];
    const float* W1 = (const float*)d_in[9];
    const float* b1 = (const float*)d_in[10];
    const float* W2 = (const float*)d_in[11];
    const float* b2 = (const float*)d_in[12];
    float* out = (float*)d_out;

    u16* wbase = (u16*)d_ws;
    u16* Qb = wbase + QB_OFF;   // also Xb
    u16* Kb = wbase + KB_OFF;
    u16* Vb = wbase + VB_OFF;
    float* bqs = (float*)(wbase + BQS_OFF);

    cvt_kernel<<<704, 256, 0, stream>>>(Wq, bq, Wk, Wv, W1, W2, wbase, bqs);
    proj_qkv_kernel<<<1600, 256, 0, stream>>>(queries, keys,
                                              wbase + WQ_OFF, wbase + WK_OFF, wbase + WV_OFF,
                                              bqs, bk, bv, Qb, Kb, Vb);
    attn_kernel<<<B_ * 4, 256, 0, stream>>>(Qb, Kb, Vb, mask, queries, Qb);
    ffn_kernel<<<800, 256, 0, stream>>>(Qb, wbase + W1_OFF, wbase + W2_OFF, b1, b2, out);
}

// Round 22
// 126.802 us; speedup vs baseline: 1.0454x; 1.0020x over previous
//
#include <hip/hip_runtime.h>

#define B_  512
#define S_  200
#define M_  102400

typedef short bf16x8 __attribute__((ext_vector_type(8)));
typedef float f32x4  __attribute__((ext_vector_type(4)));
typedef unsigned short u16;
typedef u16 us4 __attribute__((ext_vector_type(4)));
typedef unsigned int u32;

#define MFMA16 __builtin_amdgcn_mfma_f32_16x16x32_bf16
#define GLDS(gp, lp) __builtin_amdgcn_global_load_lds( \
    (const __attribute__((address_space(1))) unsigned int*)(gp), \
    (__attribute__((address_space(3))) unsigned int*)(lp), 16, 0, 0)

__device__ __forceinline__ u16 f2bf(float f) {
    union { float f; unsigned u; } v; v.f = f;
    unsigned r = v.u + 0x7fffu + ((v.u >> 16) & 1u);
    return (u16)(r >> 16);
}
__device__ __forceinline__ float bf2f(u16 x) {
    union { unsigned u; float f; } v; v.u = ((unsigned)x) << 16;
    return v.f;
}
__device__ __forceinline__ u32 pk(float a, float b) {   // RTZ pack 2xbf16
    return (__float_as_uint(a) >> 16) | (__float_as_uint(b) & 0xffff0000u);
}
__device__ __forceinline__ int swz(int row, int b) { return b ^ ((row & 7) << 4); }

// ws layout (u16 units)
#define WQ_OFF   0
#define WK_OFF   16384
#define WV_OFF   32768
#define W1_OFF   49152    // 8 subs x 16KB: [fr(64)][k(128)] swizzled
#define W2_OFF   114688   // 8 subs x 16KB: [out(128)][lc(64)] swizzled, lc k-permuted
#define BQS_OFF  180224
#define QB_OFF   262144   // also Xb (aliased)
#define KB_OFF   (QB_OFF + 13107200)
#define VB_OFF   (KB_OFF + 13107200)

// ---------------------------------------------------------------------------
__global__ __launch_bounds__(256) void cvt_kernel(
    const float* __restrict__ Wq, const float* __restrict__ bq,
    const float* __restrict__ Wk, const float* __restrict__ Wv,
    const float* __restrict__ W1, const float* __restrict__ W2,
    u16* __restrict__ wdst, float* __restrict__ bqs)
{
    // 1/sqrt(32) * log2(e): scores come out in exp2 domain
    const float QSC = 0.17677669529663689f * 1.4426950408889634f;
    int idx = blockIdx.x * 256 + threadIdx.x;
    if (idx < 128) bqs[idx] = bq[idx] * QSC;
    if (idx < 49152) {
        int wsel = idx >> 14, r = (idx >> 7) & 127, c = idx & 127;
        const float* src = wsel == 0 ? Wq : (wsel == 1 ? Wk : Wv);
        float v = src[idx & 16383];
        if (wsel == 0) v *= QSC;
        *(u16*)((char*)(wdst + wsel * 16384) + r * 256 + swz(r, 2 * c)) = f2bf(v);
    } else if (idx < 114688) {
        int i = idx - 49152;
        int r_g = i >> 7, c = i & 127;
        int sub = r_g >> 6, fr = r_g & 63;
        *(u16*)((char*)(wdst + W1_OFF) + sub * 16384 + fr * 256 + ((2 * c) ^ ((fr & 7) << 4)))
            = f2bf(W1[i]);
    } else if (idx < 180224) {
        int i = idx - 114688;
        int r_out = i >> 9, c_ff = i & 511;
        int sub = c_ff >> 6, o = c_ff & 63;
        int chunk = o >> 5, w32 = o & 31;
        int bb = w32 >> 4, hh = (w32 >> 2) & 3, rr = w32 & 3;
        int lc = chunk * 32 + 8 * hh + 4 * bb + rr;
        *(u16*)((char*)(wdst + W2_OFF) + sub * 16384 + r_out * 128 + ((2 * lc) ^ ((r_out & 7) << 4)))
            = f2bf(W2[i]);
    }
}

// ---------------------------------------------------------------------------
// FUSED projections (r19 base), SWAPPED-OPERAND GEMMs: lane holds 4
// consecutive output cols -> 8B us4 stores (16 per lane, was 64x2B).
// Blocks [0,800) = Q path; [800,1600) = KV path (keys read once).
// ---------------------------------------------------------------------------
__global__ __launch_bounds__(256) void proj_qkv_kernel(
    const float* __restrict__ queries, const float* __restrict__ keys,
    const u16* __restrict__ Wqs, const u16* __restrict__ Wks, const u16* __restrict__ Wvs,
    const float* __restrict__ bqs, const float* __restrict__ bk, const float* __restrict__ bv,
    u16* __restrict__ Qb, u16* __restrict__ Kb, u16* __restrict__ Vb)
{
    __shared__ __align__(16) u16 sA[16384];
    __shared__ __align__(16) u16 sB[16384];
    const int tid = threadIdx.x, w = tid >> 6, lane = tid & 63;
    const int lo = lane & 15, hi = lane >> 4;
    const int bid = blockIdx.x;

    if (bid < 800) {
        // ---------------- Q path ----------------
        const int base = bid * 128;
#pragma unroll
        for (int k = 0; k < 8; ++k) {
            int seg = w * 8 + k;
            GLDS((const char*)Wqs + seg * 1024 + lane * 16, (char*)sA + seg * 1024);
        }
        bf16x8 a[2][4];
#pragma unroll
        for (int t = 0; t < 2; ++t) {
            const float* rp = queries + (size_t)(base + w * 32 + t * 16 + lo) * 128;
#pragma unroll
            for (int ks = 0; ks < 4; ++ks) {
                float4 v0 = *(const float4*)(rp + ks * 32 + hi * 8);
                float4 v1 = *(const float4*)(rp + ks * 32 + hi * 8 + 4);
                union { bf16x8 v; u16 s[8]; } af;
                af.s[0]=f2bf(v0.x); af.s[1]=f2bf(v0.y); af.s[2]=f2bf(v0.z); af.s[3]=f2bf(v0.w);
                af.s[4]=f2bf(v1.x); af.s[5]=f2bf(v1.y); af.s[6]=f2bf(v1.z); af.s[7]=f2bf(v1.w);
                a[t][ks] = af.v;
            }
        }
        asm volatile("s_waitcnt vmcnt(0)" ::: "memory");
        __builtin_amdgcn_s_barrier();

#pragma unroll
        for (int n = 0; n < 8; ++n) {
            bf16x8 bf[4];
#pragma unroll
            for (int ks = 0; ks < 4; ++ks)
                bf[ks] = *(const bf16x8*)((const char*)sA + (n*16+lo)*256 + swz(lo, ks*64 + hi*16));
            float4 bb = *(const float4*)(bqs + n * 16 + 4 * hi);
#pragma unroll
            for (int t = 0; t < 2; ++t) {
                f32x4 acc = {0.f, 0.f, 0.f, 0.f};
                // swapped: lane holds Y[row=lo][col=n*16+4hi+r]
#pragma unroll
                for (int ks = 0; ks < 4; ++ks) acc = MFMA16(bf[ks], a[t][ks], acc, 0, 0, 0);
                int row = base + w * 32 + t * 16 + lo;
                us4 ov;
                ov[0] = f2bf(acc[0] + bb.x);
                ov[1] = f2bf(acc[1] + bb.y);
                ov[2] = f2bf(acc[2] + bb.z);
                ov[3] = f2bf(acc[3] + bb.w);
                *(us4*)((char*)Qb + (size_t)row * 256
                         + ((n * 32 + 8 * hi) ^ ((row & 7) << 4))) = ov;
            }
        }
    } else {
        // ---------------- KV path ----------------
        const int base = (bid - 800) * 128;
#pragma unroll
        for (int k = 0; k < 8; ++k) {
            int seg = w * 8 + k;
            GLDS((const char*)Wks + seg * 1024 + lane * 16, (char*)sA + seg * 1024);
            GLDS((const char*)Wvs + seg * 1024 + lane * 16, (char*)sB + seg * 1024);
        }
        bf16x8 a[2][4];
#pragma unroll
        for (int t = 0; t < 2; ++t) {
            const float* rp = keys + (size_t)(base + w * 32 + t * 16 + lo) * 128;
#pragma unroll
            for (int ks = 0; ks < 4; ++ks) {
                float4 v0 = *(const float4*)(rp + ks * 32 + hi * 8);
                float4 v1 = *(const float4*)(rp + ks * 32 + hi * 8 + 4);
                union { bf16x8 v; u16 s[8]; } af;
                af.s[0]=f2bf(v0.x); af.s[1]=f2bf(v0.y); af.s[2]=f2bf(v0.z); af.s[3]=f2bf(v0.w);
                af.s[4]=f2bf(v1.x); af.s[5]=f2bf(v1.y); af.s[6]=f2bf(v1.z); af.s[7]=f2bf(v1.w);
                a[t][ks] = af.v;
            }
        }
        asm volatile("s_waitcnt vmcnt(0)" ::: "memory");
        __builtin_amdgcn_s_barrier();

#pragma unroll
        for (int n = 0; n < 8; ++n) {
            bf16x8 bf[4];
#pragma unroll
            for (int ks = 0; ks < 4; ++ks)
                bf[ks] = *(const bf16x8*)((const char*)sA + (n*16+lo)*256 + swz(lo, ks*64 + hi*16));
            float4 bb = *(const float4*)(bk + n * 16 + 4 * hi);
#pragma unroll
            for (int t = 0; t < 2; ++t) {
                f32x4 acc = {0.f, 0.f, 0.f, 0.f};
#pragma unroll
                for (int ks = 0; ks < 4; ++ks) acc = MFMA16(bf[ks], a[t][ks], acc, 0, 0, 0);
                size_t row = base + w * 32 + t * 16 + lo;
                us4 ov;
                ov[0] = f2bf(acc[0] + bb.x);
                ov[1] = f2bf(acc[1] + bb.y);
                ov[2] = f2bf(acc[2] + bb.z);
                ov[3] = f2bf(acc[3] + bb.w);
                *(us4*)(Kb + row * 128 + n * 16 + 4 * hi) = ov;
            }
        }
#pragma unroll
        for (int n = 0; n < 8; ++n) {
            bf16x8 bf[4];
#pragma unroll
            for (int ks = 0; ks < 4; ++ks)
                bf[ks] = *(const bf16x8*)((const char*)sB + (n*16+lo)*256 + swz(lo, ks*64 + hi*16));
            float4 bb = *(const float4*)(bv + n * 16 + 4 * hi);
#pragma unroll
            for (int t = 0; t < 2; ++t) {
                f32x4 acc = {0.f, 0.f, 0.f, 0.f};
#pragma unroll
                for (int ks = 0; ks < 4; ++ks) acc = MFMA16(bf[ks], a[t][ks], acc, 0, 0, 0);
                size_t row = base + w * 32 + t * 16 + lo;
                us4 ov;
                ov[0] = f2bf(acc[0] + bb.x);
                ov[1] = f2bf(acc[1] + bb.y);
                ov[2] = f2bf(acc[2] + bb.z);
                ov[3] = f2bf(acc[3] + bb.w);
                *(us4*)(Vb + row * 128 + n * 16 + 4 * hi) = ov;
            }
        }
    }
}

// ---------------------------------------------------------------------------
// Attention: r7 structure + mask compaction (unchanged from round 11).
// ---------------------------------------------------------------------------
__global__ __launch_bounds__(256, 4) void attn_kernel(
    const u16* __restrict__ Qb, const u16* __restrict__ Kb, const u16* __restrict__ Vb,
    const int* __restrict__ mask, const float* __restrict__ queries, u16* __restrict__ Xb)
{
    __shared__ __align__(16) u16 sK[224][40];    // slot x d (pad slots zeroed)
    __shared__ __align__(16) u16 sVt[32][248];   // d x permuted slot
    __shared__ __align__(16) u16 sMk[224];       // permuted slot validity (bf16 1/0)
    __shared__ u16 sIdx[224];                    // slot -> original key
    __shared__ int sCnt4[4];

    const int bid = blockIdx.x;
    const int wg  = (bid & 7) * 256 + (bid >> 3);   // XCD-contiguous
    const int b   = wg >> 2;
    const int h   = wg & 3;
    const int tid = threadIdx.x;
    const int w = tid >> 6, lane = tid & 63;
    const int lo = lane & 15, hi = lane >> 4;
    const size_t rowbase = (size_t)b * 200;

    // phase 1: per-wave valid counts + in-wave prefix
    bool valid = (tid < 200) && (mask[rowbase + tid] != 0);
    unsigned long long bal = __ballot(valid);
    int prefix = __popcll(bal & ((1ull << lane) - 1ull));
    if (lane == 0) sCnt4[w] = __popcll(bal);
    __syncthreads();

    // phase 2a: scatter compacted indices + permuted validity mask
    int c0_ = sCnt4[0], c1_ = sCnt4[1], c2_ = sCnt4[2], c3_ = sCnt4[3];
    int off = (w > 0 ? c0_ : 0) + (w > 1 ? c1_ : 0) + (w > 2 ? c2_ : 0);
    const int cnt = c0_ + c1_ + c2_ + c3_;
    const int cntPad = (cnt + 31) & ~31;
    const int nch = cntPad >> 5;
    if (valid) sIdx[off + prefix] = (u16)tid;
    for (int i = tid; i < 224; i += 256) {
        int cb = i & ~31, local = i & 31;
        int hh = local >> 3, j = local & 7;
        int slot = cb + 16 * (j >> 2) + 4 * hh + (j & 3);
        sMk[i] = (slot < cnt) ? (u16)0x3F80 : (u16)0;
    }
    __syncthreads();

    // phase 2b: gather-stage compacted K and permuted V^T
    for (int i = tid; i < (cntPad << 2); i += 256) {
        int j = i >> 2, part = i & 3;
        bf16x8 val = {0,0,0,0,0,0,0,0};
        if (j < cnt) {
            int key = sIdx[j];
            val = *(const bf16x8*)(Kb + (rowbase + key) * 128 + h * 32 + part * 8);
        }
        *(bf16x8*)&sK[j][part * 8] = val;
    }
    for (int slot = tid; slot < (cntPad << 3); slot += 256) {
        int d = slot & 31, sg = slot >> 5;
        int s0 = sg * 4;
        int cb = s0 & ~31, a = (s0 & 31) >> 2;
        int pos = cb + (a & 3) * 8 + (a >> 2) * 4;
        us4 v;
#pragma unroll
        for (int j = 0; j < 4; ++j) {
            int s = s0 + j;
            v[j] = (s < cnt) ? Vb[(rowbase + sIdx[s]) * 128 + h * 32 + d] : (u16)0;
        }
        *(us4*)&sVt[d][pos] = v;
    }
    __syncthreads();

    for (int qb = w; qb < 13; qb += 4) {
        int qrow = qb * 16 + lo;
        if (qrow > 199) qrow = 199;
        bf16x8 qf = *(const bf16x8*)((const char*)Qb + (size_t)(rowbase + qrow) * 256
                                      + swz(qrow, h * 64 + hi * 16));

        f32x4 acc0 = {0.f, 0.f, 0.f, 0.f};
        f32x4 acc1 = {0.f, 0.f, 0.f, 0.f};
        f32x4 accs = {0.f, 0.f, 0.f, 0.f};

#pragma unroll 1
        for (int kt = 0; kt < nch; ++kt) {
            int cb = kt * 32;
            bf16x8 k0 = *(const bf16x8*)&sK[cb + lo][hi * 8];
            bf16x8 k1 = *(const bf16x8*)&sK[cb + 16 + lo][hi * 8];
            f32x4 z = {0.f, 0.f, 0.f, 0.f};
            f32x4 s0 = MFMA16(k0, qf, z, 0, 0, 0);   // S^T[slot=cb+4hi+r][q=lo]
            f32x4 s1 = MFMA16(k1, qf, z, 0, 0, 0);
            float p0 = __builtin_amdgcn_exp2f(s0[0]);
            float p1 = __builtin_amdgcn_exp2f(s0[1]);
            float p2 = __builtin_amdgcn_exp2f(s0[2]);
            float p3 = __builtin_amdgcn_exp2f(s0[3]);
            float p4 = __builtin_amdgcn_exp2f(s1[0]);
            float p5 = __builtin_amdgcn_exp2f(s1[1]);
            float p6 = __builtin_amdgcn_exp2f(s1[2]);
            float p7 = __builtin_amdgcn_exp2f(s1[3]);
            union { bf16x8 v; u32 d[4]; } pa;
            pa.d[0] = pk(p0, p1); pa.d[1] = pk(p2, p3);
            pa.d[2] = pk(p4, p5); pa.d[3] = pk(p6, p7);
            bf16x8 mkf = *(const bf16x8*)&sMk[cb + hi * 8];
            bf16x8 v0  = *(const bf16x8*)&sVt[lo][cb + hi * 8];
            bf16x8 v1  = *(const bf16x8*)&sVt[16 + lo][cb + hi * 8];
            acc0 = MFMA16(pa.v, v0, acc0, 0, 0, 0);
            acc1 = MFMA16(pa.v, v1, acc1, 0, 0, 0);
            accs = MFMA16(pa.v, mkf, accs, 0, 0, 0);   // psum[q=4hi+r] in accs[r]
        }

        float invr[4];
#pragma unroll
        for (int r = 0; r < 4; ++r) invr[r] = __builtin_amdgcn_rcpf(accs[r]);
#pragma unroll
        for (int r = 0; r < 4; ++r) {
            int row = qb * 16 + hi * 4 + r;
            if (row < 200) {
                size_t o  = (rowbase + row) * 128 + h * 32;
                size_t rb = (rowbase + row) * 256;
                *(u16*)((char*)Xb + rb + swz(row, h * 64 + 2 * lo)) =
                    f2bf(acc0[r] * invr[r] + queries[o + lo]);
                *(u16*)((char*)Xb + rb + swz(row, h * 64 + 32 + 2 * lo)) =
                    f2bf(acc1[r] * invr[r] + queries[o + 16 + lo]);
            }
        }
    }
}

// ---------------------------------------------------------------------------
// Fused FFN (r16 v4, best measured): ONE barrier per sub, full double-buffer.
// ---------------------------------------------------------------------------
__global__ __launch_bounds__(256, 2) void ffn_kernel(
    const u16* __restrict__ Xb, const u16* __restrict__ W1s, const u16* __restrict__ W2s,
    const float* __restrict__ b1, const float* __restrict__ b2, float* __restrict__ out)
{
    __shared__ __align__(16) u16 sW1[2][8192];
    __shared__ __align__(16) u16 sW2[2][8192];
    const int tid = threadIdx.x, w = tid >> 6, lane = tid & 63;
    const int lo = lane & 15, hi = lane >> 4;
    const size_t base = (size_t)blockIdx.x * 128;
    const int wrow = w * 32;

    // prologue: stage W1[0] only
#pragma unroll
    for (int k = 0; k < 4; ++k) {
        int seg = w * 4 + k;
        GLDS((const char*)W1s + seg * 1024 + lane * 16, (char*)sW1[0] + seg * 1024);
    }

    bf16x8 a[2][4];
#pragma unroll
    for (int t = 0; t < 2; ++t) {
        size_t row = base + wrow + t * 16 + lo;
#pragma unroll
        for (int ks = 0; ks < 4; ++ks)
            a[t][ks] = *(const bf16x8*)((const char*)Xb + row * 256
                                         + ((ks * 64 + hi * 16) ^ ((lo & 7) << 4)));
    }

    f32x4 yacc[2][8];
#pragma unroll
    for (int t = 0; t < 2; ++t)
#pragma unroll
        for (int n = 0; n < 8; ++n) yacc[t][n] = (f32x4){0.f, 0.f, 0.f, 0.f};

    asm volatile("s_waitcnt vmcnt(0)" ::: "memory");
    __builtin_amdgcn_s_barrier();

    bf16x8 pbPrev[2][2];

#pragma unroll 2
    for (int s = 0; s < 8; ++s) {
        const int cur = s & 1, nxt = cur ^ 1;
        // issue prefetches first (full phase to land)
        if (s < 7) {
#pragma unroll
            for (int k = 0; k < 4; ++k) {
                int seg = w * 4 + k;
                GLDS((const char*)W1s + (s + 1) * 16384 + seg * 1024 + lane * 16,
                     (char*)sW1[nxt] + seg * 1024);
            }
        }
#pragma unroll
        for (int k = 0; k < 4; ++k) {
            int seg = w * 4 + k;
            GLDS((const char*)W2s + s * 16384 + seg * 1024 + lane * 16,
                 (char*)sW2[cur] + seg * 1024);
        }
        // GEMM2(s-1): reads sW2[nxt] = sW2[(s-1)&1]
        if (s > 0) {
#pragma unroll
            for (int c = 0; c < 2; ++c) {
#pragma unroll
                for (int n = 0; n < 8; ++n) {
                    bf16x8 w2f = *(const bf16x8*)((const char*)sW2[nxt]
                                   + (n * 16 + lo) * 128
                                   + ((c * 64 + hi * 16) ^ ((lo & 7) << 4)));
                    yacc[0][n] = MFMA16(w2f, pbPrev[c][0], yacc[0][n], 0, 0, 0);
                    yacc[1][n] = MFMA16(w2f, pbPrev[c][1], yacc[1][n], 0, 0, 0);
                }
            }
        }
        // GEMM1(s): reads sW1[cur] -> pbPrev for next phase
#pragma unroll
        for (int c = 0; c < 2; ++c) {
            bf16x8 w1f[2][4];
#pragma unroll
            for (int u = 0; u < 2; ++u)
#pragma unroll
                for (int ks = 0; ks < 4; ++ks)
                    w1f[u][ks] = *(const bf16x8*)((const char*)sW1[cur]
                                   + ((2*c+u) * 16 + lo) * 256
                                   + ((ks * 64 + hi * 16) ^ ((lo & 7) << 4)));
            float4 b1v0 = *(const float4*)(b1 + s * 64 + (2*c) * 16 + 4 * hi);
            float4 b1v1 = *(const float4*)(b1 + s * 64 + (2*c+1) * 16 + 4 * hi);
#pragma unroll
            for (int t = 0; t < 2; ++t) {
                f32x4 h0 = {0.f,0.f,0.f,0.f}, h1 = {0.f,0.f,0.f,0.f};
#pragma unroll
                for (int ks = 0; ks < 4; ++ks) {
                    h0 = MFMA16(w1f[0][ks], a[t][ks], h0, 0, 0, 0);
                    h1 = MFMA16(w1f[1][ks], a[t][ks], h1, 0, 0, 0);
                }
                float p0 = fmaxf(h0[0] + b1v0.x, 0.f);
                float p1 = fmaxf(h0[1] + b1v0.y, 0.f);
                float p2 = fmaxf(h0[2] + b1v0.z, 0.f);
                float p3 = fmaxf(h0[3] + b1v0.w, 0.f);
                float p4 = fmaxf(h1[0] + b1v1.x, 0.f);
                float p5 = fmaxf(h1[1] + b1v1.y, 0.f);
                float p6 = fmaxf(h1[2] + b1v1.z, 0.f);
                float p7 = fmaxf(h1[3] + b1v1.w, 0.f);
                union { bf16x8 v; u32 d[4]; } pu;
                pu.d[0] = pk(p0, p1); pu.d[1] = pk(p2, p3);
                pu.d[2] = pk(p4, p5); pu.d[3] = pk(p6, p7);
                pbPrev[c][t] = pu.v;
            }
        }
        asm volatile("s_waitcnt vmcnt(0)" ::: "memory");
        __builtin_amdgcn_s_barrier();
    }

    // epilogue GEMM2(7): reads sW2[1] (staged+drained in phase 7)
#pragma unroll
    for (int c = 0; c < 2; ++c) {
#pragma unroll
        for (int n = 0; n < 8; ++n) {
            bf16x8 w2f = *(const bf16x8*)((const char*)sW2[1]
                           + (n * 16 + lo) * 128
                           + ((c * 64 + hi * 16) ^ ((lo & 7) << 4)));
            yacc[0][n] = MFMA16(w2f, pbPrev[c][0], yacc[0][n], 0, 0, 0);
            yacc[1][n] = MFMA16(w2f, pbPrev[c][1], yacc[1][n], 0, 0, 0);
        }
    }

    // store epilogue: lane holds Y[Xrow=wrow+t*16+lo][out=n*16+4hi+r]
#pragma unroll
    for (int t = 0; t < 2; ++t) {
        size_t row = base + wrow + t * 16 + lo;
#pragma unroll
        for (int n = 0; n < 8; ++n) {
            float4 b2v = *(const float4*)(b2 + n * 16 + 4 * hi);
            us4 rv = *(const us4*)((const char*)Xb + row * 256
                                    + ((2 * (n * 16 + 4 * hi)) ^ (((int)row & 7) << 4)));
            float4 o;
            o.x = yacc[t][n][0] + b2v.x + bf2f(rv[0]);
            o.y = yacc[t][n][1] + b2v.y + bf2f(rv[1]);
            o.z = yacc[t][n][2] + b2v.z + bf2f(rv[2]);
            o.w = yacc[t][n][3] + b2v.w + bf2f(rv[3]);
            *(float4*)(out + row * 128 + n * 16 + 4 * hi) = o;
        }
    }
}

// ---------------------------------------------------------------------------
extern "C" void kernel_launch(void* const* d_in, const int* in_sizes, int n_in,
                              void* d_out, int out_size, void* d_ws, size_t ws_size,
                              hipStream_t stream) {
    const float* queries = (const float*)d_in[0];
    const float* keys    = (const float*)d_in[1];
    const int*   mask    = (const int*)d_in[2];
    const float* Wq = (const float*)d_in[3];
    const float* bq = (const float*)d_in[4];
    const float* Wk = (const float*)d_in[5];
    const float* bk = (const float*)d_in[6];
    const float* Wv = (const float*)d_in[7];
    const float* bv = (const float*)d_in[8];
    const float* W1 = (const float*)d_in[9];
    const float* b1 = (const float*)d_in[10];
    const float* W2 = (const float*)d_in[11];
    const float* b2 = (const float*)d_in[12];
    float* out = (float*)d_out;

    u16* wbase = (u16*)d_ws;
    u16* Qb = wbase + QB_OFF;   // also Xb
    u16* Kb = wbase + KB_OFF;
    u16* Vb = wbase + VB_OFF;
    float* bqs = (float*)(wbase + BQS_OFF);

    cvt_kernel<<<704, 256, 0, stream>>>(Wq, bq, Wk, Wv, W1, W2, wbase, bqs);
    proj_qkv_kernel<<<1600, 256, 0, stream>>>(queries, keys,
                                              wbase + WQ_OFF, wbase + WK_OFF, wbase + WV_OFF,
                                              bqs, bk, bv, Qb, Kb, Vb);
    attn_kernel<<<B_ * 4, 256, 0, stream>>>(Qb, Kb, Vb, mask, queries, Qb);
    ffn_kernel<<<800, 256, 0, stream>>>(Qb, wbase + W1_OFF, wbase + W2_OFF, b1, b2, out);
}

// Round 23
// 121.325 us; speedup vs baseline: 1.0926x; 1.0451x over previous
//
#include <hip/hip_runtime.h>

#define B_  512
#define S_  200
#define M_  102400

typedef short bf16x8 __attribute__((ext_vector_type(8)));
typedef float f32x4  __attribute__((ext_vector_type(4)));
typedef unsigned short u16;
typedef u16 us4 __attribute__((ext_vector_type(4)));
typedef unsigned int u32;

#define MFMA16 __builtin_amdgcn_mfma_f32_16x16x32_bf16
#define GLDS(gp, lp) __builtin_amdgcn_global_load_lds( \
    (const __attribute__((address_space(1))) unsigned int*)(gp), \
    (__attribute__((address_space(3))) unsigned int*)(lp), 16, 0, 0)

__device__ __forceinline__ u16 f2bf(float f) {
    union { float f; unsigned u; } v; v.f = f;
    unsigned r = v.u + 0x7fffu + ((v.u >> 16) & 1u);
    return (u16)(r >> 16);
}
__device__ __forceinline__ float bf2f(u16 x) {
    union { unsigned u; float f; } v; v.u = ((unsigned)x) << 16;
    return v.f;
}
__device__ __forceinline__ u32 pk(float a, float b) {   // RTZ pack 2xbf16
    return (__float_as_uint(a) >> 16) | (__float_as_uint(b) & 0xffff0000u);
}
__device__ __forceinline__ int swz(int row, int b) { return b ^ ((row & 7) << 4); }

// ws layout (u16 units)
#define WQ_OFF   0
#define WK_OFF   16384
#define WV_OFF   32768
#define W1_OFF   49152    // 8 subs x 16KB: [fr(64)][k(128)] swizzled
#define W2_OFF   114688   // 8 subs x 16KB: [out(128)][lc(64)] swizzled, lc k-permuted
#define BQS_OFF  180224
#define QB_OFF   262144   // also Xb (aliased)
#define KB_OFF   (QB_OFF + 13107200)
#define VB_OFF   (KB_OFF + 13107200)

// ---------------------------------------------------------------------------
__global__ __launch_bounds__(256) void cvt_kernel(
    const float* __restrict__ Wq, const float* __restrict__ bq,
    const float* __restrict__ Wk, const float* __restrict__ Wv,
    const float* __restrict__ W1, const float* __restrict__ W2,
    u16* __restrict__ wdst, float* __restrict__ bqs)
{
    // 1/sqrt(32) * log2(e): scores come out in exp2 domain
    const float QSC = 0.17677669529663689f * 1.4426950408889634f;
    int idx = blockIdx.x * 256 + threadIdx.x;
    if (idx < 128) bqs[idx] = bq[idx] * QSC;
    if (idx < 49152) {
        int wsel = idx >> 14, r = (idx >> 7) & 127, c = idx & 127;
        const float* src = wsel == 0 ? Wq : (wsel == 1 ? Wk : Wv);
        float v = src[idx & 16383];
        if (wsel == 0) v *= QSC;
        *(u16*)((char*)(wdst + wsel * 16384) + r * 256 + swz(r, 2 * c)) = f2bf(v);
    } else if (idx < 114688) {
        int i = idx - 49152;
        int r_g = i >> 7, c = i & 127;
        int sub = r_g >> 6, fr = r_g & 63;
        *(u16*)((char*)(wdst + W1_OFF) + sub * 16384 + fr * 256 + ((2 * c) ^ ((fr & 7) << 4)))
            = f2bf(W1[i]);
    } else if (idx < 180224) {
        int i = idx - 114688;
        int r_out = i >> 9, c_ff = i & 511;
        int sub = c_ff >> 6, o = c_ff & 63;
        int chunk = o >> 5, w32 = o & 31;
        int bb = w32 >> 4, hh = (w32 >> 2) & 3, rr = w32 & 3;
        int lc = chunk * 32 + 8 * hh + 4 * bb + rr;
        *(u16*)((char*)(wdst + W2_OFF) + sub * 16384 + r_out * 128 + ((2 * lc) ^ ((r_out & 7) << 4)))
            = f2bf(W2[i]);
    }
}

// ---------------------------------------------------------------------------
// FUSED projections: blocks 0..799 = Q path (queries @ Wq^T -> swizzled Qb),
// blocks 800..1599 = KV path (keys @ Wk^T, Wv^T -> plain Kb, Vb).
// ---------------------------------------------------------------------------
__global__ __launch_bounds__(256) void proj_qkv_kernel(
    const float* __restrict__ queries, const float* __restrict__ keys,
    const u16* __restrict__ Wqs, const u16* __restrict__ Wks, const u16* __restrict__ Wvs,
    const float* __restrict__ bqs, const float* __restrict__ bk, const float* __restrict__ bv,
    u16* __restrict__ Qb, u16* __restrict__ Kb, u16* __restrict__ Vb)
{
    __shared__ __align__(16) u16 sA[16384];
    __shared__ __align__(16) u16 sB[16384];
    const int tid = threadIdx.x, w = tid >> 6, lane = tid & 63;
    const int lo = lane & 15, hi = lane >> 4;
    const int bid = blockIdx.x;

    if (bid < 800) {
        // ---------------- Q path ----------------
        const int base = bid * 128;
#pragma unroll
        for (int k = 0; k < 8; ++k) {
            int seg = w * 8 + k;
            GLDS((const char*)Wqs + seg * 1024 + lane * 16, (char*)sA + seg * 1024);
        }
        bf16x8 a[2][4];
#pragma unroll
        for (int t = 0; t < 2; ++t) {
            const float* rp = queries + (size_t)(base + w * 32 + t * 16 + lo) * 128;
#pragma unroll
            for (int ks = 0; ks < 4; ++ks) {
                float4 v0 = *(const float4*)(rp + ks * 32 + hi * 8);
                float4 v1 = *(const float4*)(rp + ks * 32 + hi * 8 + 4);
                union { bf16x8 v; u16 s[8]; } af;
                af.s[0]=f2bf(v0.x); af.s[1]=f2bf(v0.y); af.s[2]=f2bf(v0.z); af.s[3]=f2bf(v0.w);
                af.s[4]=f2bf(v1.x); af.s[5]=f2bf(v1.y); af.s[6]=f2bf(v1.z); af.s[7]=f2bf(v1.w);
                a[t][ks] = af.v;
            }
        }
        asm volatile("s_waitcnt vmcnt(0)" ::: "memory");
        __builtin_amdgcn_s_barrier();

#pragma unroll
        for (int n = 0; n < 8; ++n) {
            bf16x8 bf[4];
#pragma unroll
            for (int ks = 0; ks < 4; ++ks)
                bf[ks] = *(const bf16x8*)((const char*)sA + (n*16+lo)*256 + swz(lo, ks*64 + hi*16));
            float bb = bqs[n * 16 + lo];
#pragma unroll
            for (int t = 0; t < 2; ++t) {
                f32x4 acc = {0.f, 0.f, 0.f, 0.f};
#pragma unroll
                for (int ks = 0; ks < 4; ++ks) acc = MFMA16(a[t][ks], bf[ks], acc, 0, 0, 0);
#pragma unroll
                for (int r = 0; r < 4; ++r) {
                    int row = base + w * 32 + t * 16 + hi * 4 + r;
                    *(u16*)((char*)Qb + (size_t)row * 256 + swz(row, n * 32 + 2 * lo)) =
                        f2bf(acc[r] + bb);
                }
            }
        }
    } else {
        // ---------------- KV path ----------------
        const int base = (bid - 800) * 128;
#pragma unroll
        for (int k = 0; k < 8; ++k) {
            int seg = w * 8 + k;
            GLDS((const char*)Wks + seg * 1024 + lane * 16, (char*)sA + seg * 1024);
            GLDS((const char*)Wvs + seg * 1024 + lane * 16, (char*)sB + seg * 1024);
        }
        bf16x8 a[2][4];
#pragma unroll
        for (int t = 0; t < 2; ++t) {
            const float* rp = keys + (size_t)(base + w * 32 + t * 16 + lo) * 128;
#pragma unroll
            for (int ks = 0; ks < 4; ++ks) {
                float4 v0 = *(const float4*)(rp + ks * 32 + hi * 8);
                float4 v1 = *(const float4*)(rp + ks * 32 + hi * 8 + 4);
                union { bf16x8 v; u16 s[8]; } af;
                af.s[0]=f2bf(v0.x); af.s[1]=f2bf(v0.y); af.s[2]=f2bf(v0.z); af.s[3]=f2bf(v0.w);
                af.s[4]=f2bf(v1.x); af.s[5]=f2bf(v1.y); af.s[6]=f2bf(v1.z); af.s[7]=f2bf(v1.w);
                a[t][ks] = af.v;
            }
        }
        asm volatile("s_waitcnt vmcnt(0)" ::: "memory");
        __builtin_amdgcn_s_barrier();

#pragma unroll
        for (int n = 0; n < 8; ++n) {
            bf16x8 bf[4];
#pragma unroll
            for (int ks = 0; ks < 4; ++ks)
                bf[ks] = *(const bf16x8*)((const char*)sA + (n*16+lo)*256 + swz(lo, ks*64 + hi*16));
            float bb = bk[n * 16 + lo];
#pragma unroll
            for (int t = 0; t < 2; ++t) {
                f32x4 acc = {0.f, 0.f, 0.f, 0.f};
#pragma unroll
                for (int ks = 0; ks < 4; ++ks) acc = MFMA16(a[t][ks], bf[ks], acc, 0, 0, 0);
#pragma unroll
                for (int r = 0; r < 4; ++r) {
                    size_t row = base + w * 32 + t * 16 + hi * 4 + r;
                    Kb[row * 128 + n * 16 + lo] = f2bf(acc[r] + bb);
                }
            }
        }
#pragma unroll
        for (int n = 0; n < 8; ++n) {
            bf16x8 bf[4];
#pragma unroll
            for (int ks = 0; ks < 4; ++ks)
                bf[ks] = *(const bf16x8*)((const char*)sB + (n*16+lo)*256 + swz(lo, ks*64 + hi*16));
            float bb = bv[n * 16 + lo];
#pragma unroll
            for (int t = 0; t < 2; ++t) {
                f32x4 acc = {0.f, 0.f, 0.f, 0.f};
#pragma unroll
                for (int ks = 0; ks < 4; ++ks) acc = MFMA16(a[t][ks], bf[ks], acc, 0, 0, 0);
#pragma unroll
                for (int r = 0; r < 4; ++r) {
                    size_t row = base + w * 32 + t * 16 + hi * 4 + r;
                    Vb[row * 128 + n * 16 + lo] = f2bf(acc[r] + bb);
                }
            }
        }
    }
}

// ---------------------------------------------------------------------------
// Attention: r7 structure + mask compaction (round 11 config, best).
// ---------------------------------------------------------------------------
__global__ __launch_bounds__(256, 4) void attn_kernel(
    const u16* __restrict__ Qb, const u16* __restrict__ Kb, const u16* __restrict__ Vb,
    const int* __restrict__ mask, const float* __restrict__ queries, u16* __restrict__ Xb)
{
    __shared__ __align__(16) u16 sK[224][40];    // slot x d (pad slots zeroed)
    __shared__ __align__(16) u16 sVt[32][248];   // d x permuted slot
    __shared__ __align__(16) u16 sMk[224];       // permuted slot validity (bf16 1/0)
    __shared__ u16 sIdx[224];                    // slot -> original key
    __shared__ int sCnt4[4];

    const int bid = blockIdx.x;
    const int wg  = (bid & 7) * 256 + (bid >> 3);   // XCD-contiguous
    const int b   = wg >> 2;
    const int h   = wg & 3;
    const int tid = threadIdx.x;
    const int w = tid >> 6, lane = tid & 63;
    const int lo = lane & 15, hi = lane >> 4;
    const size_t rowbase = (size_t)b * 200;

    // phase 1: per-wave valid counts + in-wave prefix
    bool valid = (tid < 200) && (mask[rowbase + tid] != 0);
    unsigned long long bal = __ballot(valid);
    int prefix = __popcll(bal & ((1ull << lane) - 1ull));
    if (lane == 0) sCnt4[w] = __popcll(bal);
    __syncthreads();

    // phase 2a: scatter compacted indices + permuted validity mask
    int c0_ = sCnt4[0], c1_ = sCnt4[1], c2_ = sCnt4[2], c3_ = sCnt4[3];
    int off = (w > 0 ? c0_ : 0) + (w > 1 ? c1_ : 0) + (w > 2 ? c2_ : 0);
    const int cnt = c0_ + c1_ + c2_ + c3_;
    const int cntPad = (cnt + 31) & ~31;
    const int nch = cntPad >> 5;
    if (valid) sIdx[off + prefix] = (u16)tid;
    for (int i = tid; i < 224; i += 256) {
        int cb = i & ~31, local = i & 31;
        int hh = local >> 3, j = local & 7;
        int slot = cb + 16 * (j >> 2) + 4 * hh + (j & 3);
        sMk[i] = (slot < cnt) ? (u16)0x3F80 : (u16)0;
    }
    __syncthreads();

    // phase 2b: gather-stage compacted K and permuted V^T
    for (int i = tid; i < (cntPad << 2); i += 256) {
        int j = i >> 2, part = i & 3;
        bf16x8 val = {0,0,0,0,0,0,0,0};
        if (j < cnt) {
            int key = sIdx[j];
            val = *(const bf16x8*)(Kb + (rowbase + key) * 128 + h * 32 + part * 8);
        }
        *(bf16x8*)&sK[j][part * 8] = val;
    }
    for (int slot = tid; slot < (cntPad << 3); slot += 256) {
        int d = slot & 31, sg = slot >> 5;
        int s0 = sg * 4;
        int cb = s0 & ~31, a = (s0 & 31) >> 2;
        int pos = cb + (a & 3) * 8 + (a >> 2) * 4;
        us4 v;
#pragma unroll
        for (int j = 0; j < 4; ++j) {
            int s = s0 + j;
            v[j] = (s < cnt) ? Vb[(rowbase + sIdx[s]) * 128 + h * 32 + d] : (u16)0;
        }
        *(us4*)&sVt[d][pos] = v;
    }
    __syncthreads();

    for (int qb = w; qb < 13; qb += 4) {
        int qrow = qb * 16 + lo;
        if (qrow > 199) qrow = 199;
        bf16x8 qf = *(const bf16x8*)((const char*)Qb + (size_t)(rowbase + qrow) * 256
                                      + swz(qrow, h * 64 + hi * 16));

        f32x4 acc0 = {0.f, 0.f, 0.f, 0.f};
        f32x4 acc1 = {0.f, 0.f, 0.f, 0.f};
        f32x4 accs = {0.f, 0.f, 0.f, 0.f};

#pragma unroll 1
        for (int kt = 0; kt < nch; ++kt) {
            int cb = kt * 32;
            bf16x8 k0 = *(const bf16x8*)&sK[cb + lo][hi * 8];
            bf16x8 k1 = *(const bf16x8*)&sK[cb + 16 + lo][hi * 8];
            f32x4 z = {0.f, 0.f, 0.f, 0.f};
            f32x4 s0 = MFMA16(k0, qf, z, 0, 0, 0);   // S^T[slot=cb+4hi+r][q=lo]
            f32x4 s1 = MFMA16(k1, qf, z, 0, 0, 0);
            float p0 = __builtin_amdgcn_exp2f(s0[0]);
            float p1 = __builtin_amdgcn_exp2f(s0[1]);
            float p2 = __builtin_amdgcn_exp2f(s0[2]);
            float p3 = __builtin_amdgcn_exp2f(s0[3]);
            float p4 = __builtin_amdgcn_exp2f(s1[0]);
            float p5 = __builtin_amdgcn_exp2f(s1[1]);
            float p6 = __builtin_amdgcn_exp2f(s1[2]);
            float p7 = __builtin_amdgcn_exp2f(s1[3]);
            union { bf16x8 v; u32 d[4]; } pa;
            pa.d[0] = pk(p0, p1); pa.d[1] = pk(p2, p3);
            pa.d[2] = pk(p4, p5); pa.d[3] = pk(p6, p7);
            bf16x8 mkf = *(const bf16x8*)&sMk[cb + hi * 8];
            bf16x8 v0  = *(const bf16x8*)&sVt[lo][cb + hi * 8];
            bf16x8 v1  = *(const bf16x8*)&sVt[16 + lo][cb + hi * 8];
            acc0 = MFMA16(pa.v, v0, acc0, 0, 0, 0);
            acc1 = MFMA16(pa.v, v1, acc1, 0, 0, 0);
            accs = MFMA16(pa.v, mkf, accs, 0, 0, 0);   // psum[q=4hi+r] in accs[r]
        }

        float invr[4];
#pragma unroll
        for (int r = 0; r < 4; ++r) invr[r] = __builtin_amdgcn_rcpf(accs[r]);
#pragma unroll
        for (int r = 0; r < 4; ++r) {
            int row = qb * 16 + hi * 4 + r;
            if (row < 200) {
                size_t o  = (rowbase + row) * 128 + h * 32;
                size_t rb = (rowbase + row) * 256;
                *(u16*)((char*)Xb + rb + swz(row, h * 64 + 2 * lo)) =
                    f2bf(acc0[r] * invr[r] + queries[o + lo]);
                *(u16*)((char*)Xb + rb + swz(row, h * 64 + 32 + 2 * lo)) =
                    f2bf(acc1[r] * invr[r] + queries[o + 16 + lo]);
            }
        }
    }
}

// ---------------------------------------------------------------------------
// Fused FFN (r16 v4, best measured): ONE barrier per sub, full double-buffer.
// ---------------------------------------------------------------------------
__global__ __launch_bounds__(256, 2) void ffn_kernel(
    const u16* __restrict__ Xb, const u16* __restrict__ W1s, const u16* __restrict__ W2s,
    const float* __restrict__ b1, const float* __restrict__ b2, float* __restrict__ out)
{
    __shared__ __align__(16) u16 sW1[2][8192];
    __shared__ __align__(16) u16 sW2[2][8192];
    const int tid = threadIdx.x, w = tid >> 6, lane = tid & 63;
    const int lo = lane & 15, hi = lane >> 4;
    const size_t base = (size_t)blockIdx.x * 128;
    const int wrow = w * 32;

    // prologue: stage W1[0] only
#pragma unroll
    for (int k = 0; k < 4; ++k) {
        int seg = w * 4 + k;
        GLDS((const char*)W1s + seg * 1024 + lane * 16, (char*)sW1[0] + seg * 1024);
    }

    bf16x8 a[2][4];
#pragma unroll
    for (int t = 0; t < 2; ++t) {
        size_t row = base + wrow + t * 16 + lo;
#pragma unroll
        for (int ks = 0; ks < 4; ++ks)
            a[t][ks] = *(const bf16x8*)((const char*)Xb + row * 256
                                         + ((ks * 64 + hi * 16) ^ ((lo & 7) << 4)));
    }

    f32x4 yacc[2][8];
#pragma unroll
    for (int t = 0; t < 2; ++t)
#pragma unroll
        for (int n = 0; n < 8; ++n) yacc[t][n] = (f32x4){0.f, 0.f, 0.f, 0.f};

    asm volatile("s_waitcnt vmcnt(0)" ::: "memory");
    __builtin_amdgcn_s_barrier();

    bf16x8 pbPrev[2][2];

#pragma unroll 2
    for (int s = 0; s < 8; ++s) {
        const int cur = s & 1, nxt = cur ^ 1;
        // issue prefetches first (full phase to land)
        if (s < 7) {
#pragma unroll
            for (int k = 0; k < 4; ++k) {
                int seg = w * 4 + k;
                GLDS((const char*)W1s + (s + 1) * 16384 + seg * 1024 + lane * 16,
                     (char*)sW1[nxt] + seg * 1024);
            }
        }
#pragma unroll
        for (int k = 0; k < 4; ++k) {
            int seg = w * 4 + k;
            GLDS((const char*)W2s + s * 16384 + seg * 1024 + lane * 16,
                 (char*)sW2[cur] + seg * 1024);
        }
        // GEMM2(s-1): reads sW2[nxt] = sW2[(s-1)&1]
        if (s > 0) {
#pragma unroll
            for (int c = 0; c < 2; ++c) {
#pragma unroll
                for (int n = 0; n < 8; ++n) {
                    bf16x8 w2f = *(const bf16x8*)((const char*)sW2[nxt]
                                   + (n * 16 + lo) * 128
                                   + ((c * 64 + hi * 16) ^ ((lo & 7) << 4)));
                    yacc[0][n] = MFMA16(w2f, pbPrev[c][0], yacc[0][n], 0, 0, 0);
                    yacc[1][n] = MFMA16(w2f, pbPrev[c][1], yacc[1][n], 0, 0, 0);
                }
            }
        }
        // GEMM1(s): reads sW1[cur] -> pbPrev for next phase
#pragma unroll
        for (int c = 0; c < 2; ++c) {
            bf16x8 w1f[2][4];
#pragma unroll
            for (int u = 0; u < 2; ++u)
#pragma unroll
                for (int ks = 0; ks < 4; ++ks)
                    w1f[u][ks] = *(const bf16x8*)((const char*)sW1[cur]
                                   + ((2*c+u) * 16 + lo) * 256
                                   + ((ks * 64 + hi * 16) ^ ((lo & 7) << 4)));
            float4 b1v0 = *(const float4*)(b1 + s * 64 + (2*c) * 16 + 4 * hi);
            float4 b1v1 = *(const float4*)(b1 + s * 64 + (2*c+1) * 16 + 4 * hi);
#pragma unroll
            for (int t = 0; t < 2; ++t) {
                f32x4 h0 = {0.f,0.f,0.f,0.f}, h1 = {0.f,0.f,0.f,0.f};
#pragma unroll
                for (int ks = 0; ks < 4; ++ks) {
                    h0 = MFMA16(w1f[0][ks], a[t][ks], h0, 0, 0, 0);
                    h1 = MFMA16(w1f[1][ks], a[t][ks], h1, 0, 0, 0);
                }
                float p0 = fmaxf(h0[0] + b1v0.x, 0.f);
                float p1 = fmaxf(h0[1] + b1v0.y, 0.f);
                float p2 = fmaxf(h0[2] + b1v0.z, 0.f);
                float p3 = fmaxf(h0[3] + b1v0.w, 0.f);
                float p4 = fmaxf(h1[0] + b1v1.x, 0.f);
                float p5 = fmaxf(h1[1] + b1v1.y, 0.f);
                float p6 = fmaxf(h1[2] + b1v1.z, 0.f);
                float p7 = fmaxf(h1[3] + b1v1.w, 0.f);
                union { bf16x8 v; u32 d[4]; } pu;
                pu.d[0] = pk(p0, p1); pu.d[1] = pk(p2, p3);
                pu.d[2] = pk(p4, p5); pu.d[3] = pk(p6, p7);
                pbPrev[c][t] = pu.v;
            }
        }
        asm volatile("s_waitcnt vmcnt(0)" ::: "memory");
        __builtin_amdgcn_s_barrier();
    }

    // epilogue GEMM2(7): reads sW2[1] (staged+drained in phase 7)
#pragma unroll
    for (int c = 0; c < 2; ++c) {
#pragma unroll
        for (int n = 0; n < 8; ++n) {
            bf16x8 w2f = *(const bf16x8*)((const char*)sW2[1]
                           + (n * 16 + lo) * 128
                           + ((c * 64 + hi * 16) ^ ((lo & 7) << 4)));
            yacc[0][n] = MFMA16(w2f, pbPrev[c][0], yacc[0][n], 0, 0, 0);
            yacc[1][n] = MFMA16(w2f, pbPrev[c][1], yacc[1][n], 0, 0, 0);
        }
    }

    // store epilogue: lane holds Y[Xrow=wrow+t*16+lo][out=n*16+4hi+r]
#pragma unroll
    for (int t = 0; t < 2; ++t) {
        size_t row = base + wrow + t * 16 + lo;
#pragma unroll
        for (int n = 0; n < 8; ++n) {
            float4 b2v = *(const float4*)(b2 + n * 16 + 4 * hi);
            us4 rv = *(const us4*)((const char*)Xb + row * 256
                                    + ((2 * (n * 16 + 4 * hi)) ^ (((int)row & 7) << 4)));
            float4 o;
            o.x = yacc[t][n][0] + b2v.x + bf2f(rv[0]);
            o.y = yacc[t][n][1] + b2v.y + bf2f(rv[1]);
            o.z = yacc[t][n][2] + b2v.z + bf2f(rv[2]);
            o.w = yacc[t][n][3] + b2v.w + bf2f(rv[3]);
            *(float4*)(out + row * 128 + n * 16 + 4 * hi) = o;
        }
    }
}

// ---------------------------------------------------------------------------
extern "C" void kernel_launch(void* const* d_in, const int* in_sizes, int n_in,
                              void* d_out, int out_size, void* d_ws, size_t ws_size,
                              hipStream_t stream) {
    const float* queries = (const float*)d_in[0];
    const float* keys    = (const float*)d_in[1];
    const int*   mask    = (const int*)d_in[2];
    const float* Wq = (const float*)d_in[3];
    const float* bq = (const float*)d_in[4];
    const float* Wk = (const float*)d_in[5];
    const float* bk = (const float*)d_in[6];
    const float* Wv = (const float*)d_in[7];
    const float* bv = (const float*)d_in[8];
    const float* W1 = (const float*)d_in[9];
    const float* b1 = (const float*)d_in[10];
    const float* W2 = (const float*)d_in[11];
    const float* b2 = (const float*)d_in[12];
    float* out = (float*)d_out;

    u16* wbase = (u16*)d_ws;
    u16* Qb = wbase + QB_OFF;   // also Xb
    u16* Kb = wbase + KB_OFF;
    u16* Vb = wbase + VB_OFF;
    float* bqs = (float*)(wbase + BQS_OFF);

    cvt_kernel<<<704, 256, 0, stream>>>(Wq, bq, Wk, Wv, W1, W2, wbase, bqs);
    proj_qkv_kernel<<<1600, 256, 0, stream>>>(queries, keys,
                                              wbase + WQ_OFF, wbase + WK_OFF, wbase + WV_OFF,
                                              bqs, bk, bv, Qb, Kb, Vb);
    attn_kernel<<<B_ * 4, 256, 0, stream>>>(Qb, Kb, Vb, mask, queries, Qb);
    ffn_kernel<<<800, 256, 0, stream>>>(Qb, wbase + W1_OFF, wbase + W2_OFF, b1, b2, out);
}